// Round 6
// baseline (195.207 us; speedup 1.0000x reference)
//
#include <hip/hip_runtime.h>
#include <hip/hip_bf16.h>

constexpr int NB   = 32;
constexpr int NENV = 8;
constexpr int F0   = 16;
constexpr int F1   = 32;
constexpr int D    = 256;
constexpr int PAIRS = 128 * 64;   // 8192
constexpr float CUT = 5.0f;
constexpr int WT_STRIDE = 264;    // ushorts per row of Wt (16B aligned, breaks 512B aliasing)

typedef float f32x4 __attribute__((ext_vector_type(4)));
typedef short s16x8 __attribute__((ext_vector_type(8)));

__device__ __forceinline__ float fast_rcp(float x) { return __builtin_amdgcn_rcpf(x); }
__device__ __forceinline__ float silu(float a) {
  return a * fast_rcp(1.0f + __expf(-a));
}
__device__ __forceinline__ float fast_tanh(float t) {
  return 1.0f - 2.0f * fast_rcp(__expf(2.0f * t) + 1.0f);
}
__device__ __forceinline__ unsigned short f2bf(float f) {
  __hip_bfloat16 h = __float2bfloat16(f);
  unsigned short u; __builtin_memcpy(&u, &h, 2); return u;
}

// ---------------------------------------------------------------------------
// Kernel A (phases 1-2). One wave per (b,e) pair.
// Phase 2 nt-loop: 4 MFMAs per d-tile -- gammaM (beta@G) AND pre-activation
// (inp@d1k + bias via k-row trick), silu+Hadamard+reduce on VALU.
// Blocks 0..63 additionally transpose+convert out_kernel -> Wt bf16 in ws.
// ---------------------------------------------------------------------------
__global__ __launch_bounds__(256, 4) void moon_phase12(
    const float* __restrict__ r,            // [8192,3]
    const float* __restrict__ r_nb,         // [8192,32,3]
    const float* __restrict__ ee_scales,    // [8]
    const float* __restrict__ ee_kernel,    // [4,16]
    const float* __restrict__ ee_bias,      // [16]
    const float* __restrict__ beta_kernel,  // [24,32]
    const float* __restrict__ beta_bias,    // [32]
    const float* __restrict__ gamma_kernel, // [32,256]
    const float* __restrict__ dense1_kernel,// [4,256]
    const float* __restrict__ dense1_bias,  // [256]
    const float* __restrict__ out_kernel,   // [256,256] (for Wt conversion)
    unsigned short* __restrict__ resh,      // [8192,256] bf16 ws
    unsigned short* __restrict__ wt)        // [256, WT_STRIDE] bf16 ws (W^T)
{
  __shared__ float s_eek[4 * F0];
  __shared__ float s_eeb[F0];
  __shared__ float s_bk[(F0 + NENV) * F1];          // 768
  __shared__ float s_bb[F1];
  __shared__ float s_is2[NENV];
  __shared__ unsigned short s_ghT[4][D * 8];        // [kslot g][d][8] bf16 (16 KB)
  __shared__ unsigned short s_d1kT[D * 8];          // [d][8] bf16: d1k rows 0..3, bias at k=4 (4 KB)
  __shared__ unsigned short s_betah[4][4][NB * 8];  // [wave][g][n][8] bf16 (8 KB)
  // per-wave scratch: first used as inp A-frags (bf16, 512 B), later as fp32 res (1 KB)
  __shared__ float4 s_scratch[4][64];               // 4 KB, 16B aligned

  const int tid = threadIdx.x;
  const int w   = tid >> 6;
  const int l   = tid & 63;
  const int be  = blockIdx.x * 4 + w;

  unsigned short* s_inph = (unsigned short*)&s_scratch[w][0];  // [n][8] bf16
  float*          s_resw = (float*)&s_scratch[w][0];           // [256] fp32

  // ---- distributed W -> Wt bf16 conversion over the first 64 blocks ----
  if (blockIdx.x < 64) {
    const int i  = blockIdx.x * 256 + tid;   // [0, 16384)
    const int d  = i >> 6;                   // 0..255
    const int kg = i & 63;                   // 0..63
    ushort4 p;
    p.x = f2bf(out_kernel[(4 * kg + 0) * D + d]);
    p.y = f2bf(out_kernel[(4 * kg + 1) * D + d]);
    p.z = f2bf(out_kernel[(4 * kg + 2) * D + d]);
    p.w = f2bf(out_kernel[(4 * kg + 3) * D + d]);
    *(ushort4*)&wt[d * WT_STRIDE + 4 * kg] = p;
  }

  // ---- staging: small weights ----
  for (int i = tid; i < 888; i += 256) {
    if (i < 64)        s_eek[i]       = ee_kernel[i];
    else if (i < 80)   s_eeb[i - 64]  = ee_bias[i - 64];
    else if (i < 848)  s_bk[i - 80]   = beta_kernel[i - 80];
    else if (i < 880)  s_bb[i - 848]  = beta_bias[i - 848];
    else { float s = ee_scales[i - 880]; s_is2[i - 880] = 1.0f / (s * s); }
  }
  // ---- staging: gamma -> bf16 transposed, k-chunked (thread t owns row d=t) ----
  {
    const int d = tid;
    unsigned int pk[16];
    #pragma unroll
    for (int k2 = 0; k2 < 16; ++k2) {
      unsigned short lo = f2bf(gamma_kernel[(2 * k2 + 0) * D + d]);
      unsigned short hi = f2bf(gamma_kernel[(2 * k2 + 1) * D + d]);
      pk[k2] = (unsigned int)lo | ((unsigned int)hi << 16);
    }
    #pragma unroll
    for (int g = 0; g < 4; ++g)
      *(uint4*)&s_ghT[g][d * 8] = make_uint4(pk[4*g], pk[4*g+1], pk[4*g+2], pk[4*g+3]);
  }
  // ---- staging: d1kT b-frag (k-slots: d1k rows 0..3, bias at k=4, zeros 5..7) ----
  {
    const int d = tid;
    unsigned int p0 = (unsigned int)f2bf(dense1_kernel[0 * D + d])
                    | ((unsigned int)f2bf(dense1_kernel[1 * D + d]) << 16);
    unsigned int p1 = (unsigned int)f2bf(dense1_kernel[2 * D + d])
                    | ((unsigned int)f2bf(dense1_kernel[3 * D + d]) << 16);
    unsigned int p2 = (unsigned int)f2bf(dense1_bias[d]);   // k=4; k=5 zero
    *(uint4*)&s_d1kT[d * 8] = make_uint4(p0, p1, p2, 0u);
  }

  __syncthreads();

  // ---- phase 1: pairwise filter -> s_betah[w] (bf16), s_inph (bf16 A-frag) ----
  {
    const int n  = l & 31;
    const int cg = l >> 5;
    float rx = r[be * 3 + 0];
    float ry = r[be * 3 + 1];
    float rz = r[be * 3 + 2];
    const float* rn = r_nb + (be * NB + n) * 3;
    float dx = rn[0] - rx;
    float dy = rn[1] - ry;
    float dz = rn[2] - rz;
    float d2 = dx * dx + dy * dy + dz * dz;
    float dist = sqrtf(d2);
    float feats[4] = {dist, dx, dy, dz};
    float h[F0];
    #pragma unroll
    for (int j = 0; j < F0; ++j) {
      float t = s_eeb[j];
      #pragma unroll
      for (int i = 0; i < 4; ++i) t += feats[i] * s_eek[i * F0 + j];
      h[j] = fast_tanh(t);
    }
    float env[NENV];
    #pragma unroll
    for (int s = 0; s < NENV; ++s) env[s] = __expf(-d2 * s_is2[s]);
    float xc = dist * (1.0f / CUT);
    float fcut = (xc < 1.0f)
               ? 0.5f * (__cosf(3.14159265358979323846f * xc) + 1.0f)
               : 0.0f;
    if (cg == 0) {
      float lp = log1pf(dist);
      float inv = lp / dist;
      // A-frag k-slots: lp, dx', dy', dz', 1.0(bias), 0,0,0
      unsigned int q0 = (unsigned int)f2bf(lp) | ((unsigned int)f2bf(dx * inv) << 16);
      unsigned int q1 = (unsigned int)f2bf(dy * inv) | ((unsigned int)f2bf(dz * inv) << 16);
      *(uint4*)&s_inph[n * 8] = make_uint4(q0, q1, 0x3F80u /*bf16 1.0 at k=4*/, 0u);
    }
    unsigned int pk[8];
    #pragma unroll
    for (int c4 = 0; c4 < 4; ++c4) {
      float bb[4];
      #pragma unroll
      for (int cc = 0; cc < 4; ++cc) {
        int c = cg * 16 + c4 * 4 + cc;
        float a = s_bb[c];
        #pragma unroll
        for (int k = 0; k < F0; ++k) a += h[k] * s_bk[k * F1 + c];
        #pragma unroll
        for (int s = 0; s < NENV; ++s) a += env[s] * s_bk[(F0 + s) * F1 + c];
        bb[cc] = a * fcut;
      }
      pk[c4 * 2 + 0] = (unsigned int)f2bf(bb[0]) | ((unsigned int)f2bf(bb[1]) << 16);
      pk[c4 * 2 + 1] = (unsigned int)f2bf(bb[2]) | ((unsigned int)f2bf(bb[3]) << 16);
    }
    *(uint4*)&s_betah[w][2 * cg + 0][n * 8] = make_uint4(pk[0], pk[1], pk[2], pk[3]);
    *(uint4*)&s_betah[w][2 * cg + 1][n * 8] = make_uint4(pk[4], pk[5], pk[6], pk[7]);
  }
  __syncthreads();

  // ---- phase 2: per d-tile: c = beta@G (MFMA), f = inp@d1k+b (MFMA),
  //      p += silu(f)*c, reduce over n ----
  const int li = l & 15;          // d-within-tile / m-within-tile
  const int g  = l >> 4;          // k-slot group (and C row group)

  s16x8 a0 = *(const s16x8*)&s_betah[w][g][(0 * 16 + li) * 8];
  s16x8 a1 = *(const s16x8*)&s_betah[w][g][(1 * 16 + li) * 8];

  // inp A-frags: only g==0 chunk nonzero (k=0..4 of 32)
  s16x8 zi = {0, 0, 0, 0, 0, 0, 0, 0};
  s16x8 ai0 = zi, ai1 = zi;
  if (g == 0) {
    ai0 = *(const s16x8*)&s_inph[(0 * 16 + li) * 8];
    ai1 = *(const s16x8*)&s_inph[(1 * 16 + li) * 8];
  }

  float rpart[16];
  #pragma unroll
  for (int nt = 0; nt < 16; ++nt) {
    const int d = nt * 16 + li;
    s16x8 b = *(const s16x8*)&s_ghT[g][d * 8];
    s16x8 bd = zi;
    if (g == 0) bd = *(const s16x8*)&s_d1kT[d * 8];
    f32x4 z = {0.f, 0.f, 0.f, 0.f};
    f32x4 c0 = __builtin_amdgcn_mfma_f32_16x16x32_bf16(a0, b, z, 0, 0, 0);
    f32x4 c1 = __builtin_amdgcn_mfma_f32_16x16x32_bf16(a1, b, z, 0, 0, 0);
    f32x4 f0 = __builtin_amdgcn_mfma_f32_16x16x32_bf16(ai0, bd, z, 0, 0, 0);
    f32x4 f1 = __builtin_amdgcn_mfma_f32_16x16x32_bf16(ai1, bd, z, 0, 0, 0);
    float p = 0.f;
    #pragma unroll
    for (int reg = 0; reg < 4; ++reg) {
      p += silu(f0[reg]) * c0[reg];
      p += silu(f1[reg]) * c1[reg];
    }
    rpart[nt] = p;
  }
  #pragma unroll
  for (int nt = 0; nt < 16; ++nt) {
    float v = rpart[nt];
    v += __shfl_xor(v, 16);
    v += __shfl_xor(v, 32);
    rpart[nt] = v;
  }
  // transpose via wave-local scratch (s_inph fully consumed above; in-order LDS pipe)
  #pragma unroll
  for (int nt = 0; nt < 16; ++nt) {
    if (g == (nt & 3)) s_resw[nt * 16 + li] = rpart[nt];
  }
  float4 rv = *(const float4*)&s_resw[4 * l];
  ushort4 rp;
  rp.x = f2bf(rv.x); rp.y = f2bf(rv.y); rp.z = f2bf(rv.z); rp.w = f2bf(rv.w);
  *(ushort4*)(resh + be * D + 4 * l) = rp;
}

// ---------------------------------------------------------------------------
// Kernel B: out = silu(res @ W + b), bf16 MFMA, LDS-free.
// 1024 blocks; block = 16 rows x 128 cols; wave w covers cols [w*32, w*32+32)
// of its half -> 4096 waves total (16 waves/CU) for latency hiding.
// ---------------------------------------------------------------------------
__global__ __launch_bounds__(256, 4) void moon_outgemm(
    const unsigned short* __restrict__ resh, // [8192,256] bf16
    const unsigned short* __restrict__ wt,   // [256,WT_STRIDE] bf16 (W^T)
    const float* __restrict__ bias,          // [256]
    float* __restrict__ out)                 // [8192,256]
{
  const int tid  = threadIdx.x;
  const int w    = tid >> 6;
  const int l    = tid & 63;
  const int li   = l & 15;
  const int g    = l >> 4;
  const int tile = blockIdx.x >> 1;
  const int half = blockIdx.x & 1;
  const int row0 = tile * 16;
  const int col0 = half * 128 + w * 32;   // this wave: cols [col0, col0+32)

  float bi[2];
  #pragma unroll
  for (int nt = 0; nt < 2; ++nt) bi[nt] = bias[col0 + nt * 16 + li];

  f32x4 acc[2] = {{0.f,0.f,0.f,0.f},{0.f,0.f,0.f,0.f}};
  const unsigned short* ap = resh + (row0 + li) * D + g * 8;
  const unsigned short* bp = wt + (col0 + li) * WT_STRIDE + g * 8;

  #pragma unroll
  for (int ks = 0; ks < 8; ++ks) {
    s16x8 a = *(const s16x8*)(ap + ks * 32);
    #pragma unroll
    for (int nt = 0; nt < 2; ++nt) {
      s16x8 b = *(const s16x8*)(bp + nt * 16 * WT_STRIDE + ks * 32);
      acc[nt] = __builtin_amdgcn_mfma_f32_16x16x32_bf16(a, b, acc[nt], 0, 0, 0);
    }
  }
  #pragma unroll
  for (int nt = 0; nt < 2; ++nt) {
    #pragma unroll
    for (int reg = 0; reg < 4; ++reg) {
      int row = row0 + g * 4 + reg;
      int col = col0 + nt * 16 + li;
      out[row * D + col] = silu(acc[nt][reg] + bi[nt]);
    }
  }
}

extern "C" void kernel_launch(void* const* d_in, const int* in_sizes, int n_in,
                              void* d_out, int out_size, void* d_ws, size_t ws_size,
                              hipStream_t stream) {
  const float* r            = (const float*)d_in[0];
  const float* r_nb         = (const float*)d_in[1];
  const float* ee_scales    = (const float*)d_in[2];
  const float* ee_kernel    = (const float*)d_in[3];
  const float* ee_bias      = (const float*)d_in[4];
  const float* beta_kernel  = (const float*)d_in[5];
  const float* beta_bias    = (const float*)d_in[6];
  const float* gamma_kernel = (const float*)d_in[7];
  const float* dense1_kernel= (const float*)d_in[8];
  const float* dense1_bias  = (const float*)d_in[9];
  const float* out_kernel   = (const float*)d_in[10];
  const float* out_bias     = (const float*)d_in[11];
  float* out = (float*)d_out;

  unsigned short* resh = (unsigned short*)d_ws;                            // 4 MB bf16
  unsigned short* wt   = (unsigned short*)((char*)d_ws + 4 * 1024 * 1024); // 132 KB bf16

  hipLaunchKernelGGL(moon_phase12, dim3(PAIRS / 4), dim3(256), 0, stream,
                     r, r_nb, ee_scales, ee_kernel, ee_bias,
                     beta_kernel, beta_bias, gamma_kernel,
                     dense1_kernel, dense1_bias, out_kernel, resh, wt);
  hipLaunchKernelGGL(moon_outgemm, dim3(PAIRS / 16 * 2), dim3(256), 0, stream,
                     resh, wt, out_bias, out);
}

// Round 7
// 124.585 us; speedup vs baseline: 1.5669x; 1.5669x over previous
//
#include <hip/hip_runtime.h>
#include <hip/hip_bf16.h>

constexpr int NB   = 32;
constexpr int NENV = 8;
constexpr int F0   = 16;
constexpr int F1   = 32;
constexpr int D    = 256;
constexpr int PAIRS = 128 * 64;   // 8192
constexpr float CUT = 5.0f;
constexpr int WT_STRIDE = 264;    // ushorts per row of Wt (16B aligned, breaks 512B aliasing)

typedef float f32x4 __attribute__((ext_vector_type(4)));
typedef short s16x8 __attribute__((ext_vector_type(8)));

__device__ __forceinline__ float fast_rcp(float x) { return __builtin_amdgcn_rcpf(x); }
__device__ __forceinline__ float silu(float a) {
  return a * fast_rcp(1.0f + __expf(-a));
}
__device__ __forceinline__ float fast_tanh(float t) {
  return 1.0f - 2.0f * fast_rcp(__expf(2.0f * t) + 1.0f);
}
__device__ __forceinline__ unsigned short f2bf(float f) {
  __hip_bfloat16 h = __float2bfloat16(f);
  unsigned short u; __builtin_memcpy(&u, &h, 2); return u;
}

// ---------------------------------------------------------------------------
// Kernel A (phases 1-2). One wave per (b,e) pair.
// Phase 2: per d-tile, MFMA computes BOTH beta@G and the dense1 pre-activation
// (inp@d1k + bias via k-row trick). The inp/d1kT fragments are REPLICATED
// across the 4 k-chunk groups (each group contributes the full K=5 dot, so the
// MFMA yields 4x the value); d1kT is pre-scaled by 0.25 (bf16-exact) to cancel.
// This keeps every fragment load a plain rematerializable LDS read -- the
// r6 conditional (g==0 ? load : 0) fragments caused scratch spilling
// (WRITE_SIZE 303 MB).
// Blocks 0..63 additionally transpose+convert out_kernel -> Wt bf16 in ws.
// ---------------------------------------------------------------------------
__global__ __launch_bounds__(256)
__attribute__((amdgpu_waves_per_eu(4, 4)))
void moon_phase12(
    const float* __restrict__ r,            // [8192,3]
    const float* __restrict__ r_nb,         // [8192,32,3]
    const float* __restrict__ ee_scales,    // [8]
    const float* __restrict__ ee_kernel,    // [4,16]
    const float* __restrict__ ee_bias,      // [16]
    const float* __restrict__ beta_kernel,  // [24,32]
    const float* __restrict__ beta_bias,    // [32]
    const float* __restrict__ gamma_kernel, // [32,256]
    const float* __restrict__ dense1_kernel,// [4,256]
    const float* __restrict__ dense1_bias,  // [256]
    const float* __restrict__ out_kernel,   // [256,256] (for Wt conversion)
    unsigned short* __restrict__ resh,      // [8192,256] bf16 ws
    unsigned short* __restrict__ wt)        // [256, WT_STRIDE] bf16 ws (W^T)
{
  __shared__ float s_eek[4 * F0];
  __shared__ float s_eeb[F0];
  __shared__ float s_bk[(F0 + NENV) * F1];          // 768
  __shared__ float s_bb[F1];
  __shared__ float s_is2[NENV];
  __shared__ unsigned short s_ghT[4][D * 8];        // [kslot g][d][8] bf16 (16 KB)
  __shared__ unsigned short s_d1kT[D * 8];          // [d][8] bf16 x0.25: rows 0..3, bias at k=4 (4 KB)
  __shared__ unsigned short s_betah[4][4][NB * 8];  // [wave][g][n][8] bf16 (8 KB)
  __shared__ unsigned short s_inph[4][NB * 8];      // [wave][n][8] bf16 A-frag (2 KB)
  __shared__ float s_res[4][D];                     // [wave][256] fp32 (4 KB)

  const int tid = threadIdx.x;
  const int w   = tid >> 6;
  const int l   = tid & 63;
  const int be  = blockIdx.x * 4 + w;

  // ---- distributed W -> Wt bf16 conversion over the first 64 blocks ----
  if (blockIdx.x < 64) {
    const int i  = blockIdx.x * 256 + tid;   // [0, 16384)
    const int d  = i >> 6;                   // 0..255
    const int kg = i & 63;                   // 0..63
    ushort4 p;
    p.x = f2bf(out_kernel[(4 * kg + 0) * D + d]);
    p.y = f2bf(out_kernel[(4 * kg + 1) * D + d]);
    p.z = f2bf(out_kernel[(4 * kg + 2) * D + d]);
    p.w = f2bf(out_kernel[(4 * kg + 3) * D + d]);
    *(ushort4*)&wt[d * WT_STRIDE + 4 * kg] = p;
  }

  // ---- staging: small weights ----
  for (int i = tid; i < 888; i += 256) {
    if (i < 64)        s_eek[i]       = ee_kernel[i];
    else if (i < 80)   s_eeb[i - 64]  = ee_bias[i - 64];
    else if (i < 848)  s_bk[i - 80]   = beta_kernel[i - 80];
    else if (i < 880)  s_bb[i - 848]  = beta_bias[i - 848];
    else { float s = ee_scales[i - 880]; s_is2[i - 880] = 1.0f / (s * s); }
  }
  // ---- staging: gamma -> bf16 transposed, k-chunked (thread t owns row d=t) ----
  {
    const int d = tid;
    unsigned int pk[16];
    #pragma unroll
    for (int k2 = 0; k2 < 16; ++k2) {
      unsigned short lo = f2bf(gamma_kernel[(2 * k2 + 0) * D + d]);
      unsigned short hi = f2bf(gamma_kernel[(2 * k2 + 1) * D + d]);
      pk[k2] = (unsigned int)lo | ((unsigned int)hi << 16);
    }
    #pragma unroll
    for (int g = 0; g < 4; ++g)
      *(uint4*)&s_ghT[g][d * 8] = make_uint4(pk[4*g], pk[4*g+1], pk[4*g+2], pk[4*g+3]);
  }
  // ---- staging: d1kT b-frag, PRE-SCALED by 0.25 (replication cancel; exact) ----
  {
    const int d = tid;
    unsigned int p0 = (unsigned int)f2bf(0.25f * dense1_kernel[0 * D + d])
                    | ((unsigned int)f2bf(0.25f * dense1_kernel[1 * D + d]) << 16);
    unsigned int p1 = (unsigned int)f2bf(0.25f * dense1_kernel[2 * D + d])
                    | ((unsigned int)f2bf(0.25f * dense1_kernel[3 * D + d]) << 16);
    unsigned int p2 = (unsigned int)f2bf(0.25f * dense1_bias[d]);  // k=4; k=5..7 zero
    *(uint4*)&s_d1kT[d * 8] = make_uint4(p0, p1, p2, 0u);
  }

  __syncthreads();

  // ---- phase 1: pairwise filter -> s_betah[w] (bf16), s_inph[w] (bf16 A-frag) ----
  {
    const int n  = l & 31;
    const int cg = l >> 5;
    float rx = r[be * 3 + 0];
    float ry = r[be * 3 + 1];
    float rz = r[be * 3 + 2];
    const float* rn = r_nb + (be * NB + n) * 3;
    float dx = rn[0] - rx;
    float dy = rn[1] - ry;
    float dz = rn[2] - rz;
    float d2 = dx * dx + dy * dy + dz * dz;
    float dist = sqrtf(d2);
    float feats[4] = {dist, dx, dy, dz};
    float h[F0];
    #pragma unroll
    for (int j = 0; j < F0; ++j) {
      float t = s_eeb[j];
      #pragma unroll
      for (int i = 0; i < 4; ++i) t += feats[i] * s_eek[i * F0 + j];
      h[j] = fast_tanh(t);
    }
    float env[NENV];
    #pragma unroll
    for (int s = 0; s < NENV; ++s) env[s] = __expf(-d2 * s_is2[s]);
    float xc = dist * (1.0f / CUT);
    float fcut = (xc < 1.0f)
               ? 0.5f * (__cosf(3.14159265358979323846f * xc) + 1.0f)
               : 0.0f;
    if (cg == 0) {
      float lp = log1pf(dist);
      float inv = lp / dist;
      // A-frag k-slots: lp, dx', dy', dz', 1.0(bias), 0,0,0
      unsigned int q0 = (unsigned int)f2bf(lp) | ((unsigned int)f2bf(dx * inv) << 16);
      unsigned int q1 = (unsigned int)f2bf(dy * inv) | ((unsigned int)f2bf(dz * inv) << 16);
      *(uint4*)&s_inph[w][n * 8] = make_uint4(q0, q1, 0x3F80u /*bf16 1.0 at k=4*/, 0u);
    }
    unsigned int pk[8];
    #pragma unroll
    for (int c4 = 0; c4 < 4; ++c4) {
      float bb[4];
      #pragma unroll
      for (int cc = 0; cc < 4; ++cc) {
        int c = cg * 16 + c4 * 4 + cc;
        float a = s_bb[c];
        #pragma unroll
        for (int k = 0; k < F0; ++k) a += h[k] * s_bk[k * F1 + c];
        #pragma unroll
        for (int s = 0; s < NENV; ++s) a += env[s] * s_bk[(F0 + s) * F1 + c];
        bb[cc] = a * fcut;
      }
      pk[c4 * 2 + 0] = (unsigned int)f2bf(bb[0]) | ((unsigned int)f2bf(bb[1]) << 16);
      pk[c4 * 2 + 1] = (unsigned int)f2bf(bb[2]) | ((unsigned int)f2bf(bb[3]) << 16);
    }
    *(uint4*)&s_betah[w][2 * cg + 0][n * 8] = make_uint4(pk[0], pk[1], pk[2], pk[3]);
    *(uint4*)&s_betah[w][2 * cg + 1][n * 8] = make_uint4(pk[4], pk[5], pk[6], pk[7]);
  }
  __syncthreads();

  // ---- phase 2: per d-tile: c = beta@G (MFMA), f = inp@d1k+b (MFMA, replicated),
  //      p = sum_n silu(f)*c via shfl-reduce, write into s_res ----
  const int li = l & 15;          // d-within-tile / m-within-tile
  const int g  = l >> 4;          // k-slot group (and C row group)

  s16x8 a0 = *(const s16x8*)&s_betah[w][g][(0 * 16 + li) * 8];
  s16x8 a1 = *(const s16x8*)&s_betah[w][g][(1 * 16 + li) * 8];
  // replicated inp A-frags: same data for every g (plain broadcast LDS reads)
  s16x8 ai0 = *(const s16x8*)&s_inph[w][(0 * 16 + li) * 8];
  s16x8 ai1 = *(const s16x8*)&s_inph[w][(1 * 16 + li) * 8];

  #pragma unroll 4
  for (int nt = 0; nt < 16; ++nt) {
    const int d = nt * 16 + li;
    s16x8 b  = *(const s16x8*)&s_ghT[g][d * 8];
    s16x8 bd = *(const s16x8*)&s_d1kT[d * 8];    // replicated across g (x0.25 pre-scaled)
    f32x4 z = {0.f, 0.f, 0.f, 0.f};
    f32x4 c0 = __builtin_amdgcn_mfma_f32_16x16x32_bf16(a0, b, z, 0, 0, 0);
    f32x4 c1 = __builtin_amdgcn_mfma_f32_16x16x32_bf16(a1, b, z, 0, 0, 0);
    f32x4 f0 = __builtin_amdgcn_mfma_f32_16x16x32_bf16(ai0, bd, z, 0, 0, 0);
    f32x4 f1 = __builtin_amdgcn_mfma_f32_16x16x32_bf16(ai1, bd, z, 0, 0, 0);
    float p = 0.f;
    #pragma unroll
    for (int reg = 0; reg < 4; ++reg) {
      p += silu(f0[reg]) * c0[reg];
      p += silu(f1[reg]) * c1[reg];
    }
    // reduce over n (row groups live on lane bits 4..5)
    p += __shfl_xor(p, 16);
    p += __shfl_xor(p, 32);
    if (g == (nt & 3)) s_res[w][nt * 16 + li] = p;  // wave-local transpose write
  }
  // wave-local LDS RAW (in-order LDS pipe per wave; compiler inserts lgkmcnt)
  float4 rv = *(const float4*)&s_res[w][4 * l];
  ushort4 rp;
  rp.x = f2bf(rv.x); rp.y = f2bf(rv.y); rp.z = f2bf(rv.z); rp.w = f2bf(rv.w);
  *(ushort4*)(resh + be * D + 4 * l) = rp;
}

// ---------------------------------------------------------------------------
// Kernel B: out = silu(res @ W + b), bf16 MFMA, LDS-free (unchanged from r6;
// measured ~22 us floor, overhead/traffic-bound not TLP-bound).
// ---------------------------------------------------------------------------
__global__ __launch_bounds__(256, 4) void moon_outgemm(
    const unsigned short* __restrict__ resh, // [8192,256] bf16
    const unsigned short* __restrict__ wt,   // [256,WT_STRIDE] bf16 (W^T)
    const float* __restrict__ bias,          // [256]
    float* __restrict__ out)                 // [8192,256]
{
  const int tid  = threadIdx.x;
  const int w    = tid >> 6;
  const int l    = tid & 63;
  const int li   = l & 15;
  const int g    = l >> 4;
  const int tile = blockIdx.x >> 1;
  const int half = blockIdx.x & 1;
  const int row0 = tile * 16;
  const int col0 = half * 128 + w * 32;   // this wave: cols [col0, col0+32)

  float bi[2];
  #pragma unroll
  for (int nt = 0; nt < 2; ++nt) bi[nt] = bias[col0 + nt * 16 + li];

  f32x4 acc[2] = {{0.f,0.f,0.f,0.f},{0.f,0.f,0.f,0.f}};
  const unsigned short* ap = resh + (row0 + li) * D + g * 8;
  const unsigned short* bp = wt + (col0 + li) * WT_STRIDE + g * 8;

  #pragma unroll
  for (int ks = 0; ks < 8; ++ks) {
    s16x8 a = *(const s16x8*)(ap + ks * 32);
    #pragma unroll
    for (int nt = 0; nt < 2; ++nt) {
      s16x8 b = *(const s16x8*)(bp + nt * 16 * WT_STRIDE + ks * 32);
      acc[nt] = __builtin_amdgcn_mfma_f32_16x16x32_bf16(a, b, acc[nt], 0, 0, 0);
    }
  }
  #pragma unroll
  for (int nt = 0; nt < 2; ++nt) {
    #pragma unroll
    for (int reg = 0; reg < 4; ++reg) {
      int row = row0 + g * 4 + reg;
      int col = col0 + nt * 16 + li;
      out[row * D + col] = silu(acc[nt][reg] + bi[nt]);
    }
  }
}

extern "C" void kernel_launch(void* const* d_in, const int* in_sizes, int n_in,
                              void* d_out, int out_size, void* d_ws, size_t ws_size,
                              hipStream_t stream) {
  const float* r            = (const float*)d_in[0];
  const float* r_nb         = (const float*)d_in[1];
  const float* ee_scales    = (const float*)d_in[2];
  const float* ee_kernel    = (const float*)d_in[3];
  const float* ee_bias      = (const float*)d_in[4];
  const float* beta_kernel  = (const float*)d_in[5];
  const float* beta_bias    = (const float*)d_in[6];
  const float* gamma_kernel = (const float*)d_in[7];
  const float* dense1_kernel= (const float*)d_in[8];
  const float* dense1_bias  = (const float*)d_in[9];
  const float* out_kernel   = (const float*)d_in[10];
  const float* out_bias     = (const float*)d_in[11];
  float* out = (float*)d_out;

  unsigned short* resh = (unsigned short*)d_ws;                            // 4 MB bf16
  unsigned short* wt   = (unsigned short*)((char*)d_ws + 4 * 1024 * 1024); // 132 KB bf16

  hipLaunchKernelGGL(moon_phase12, dim3(PAIRS / 4), dim3(256), 0, stream,
                     r, r_nb, ee_scales, ee_kernel, ee_bias,
                     beta_kernel, beta_bias, gamma_kernel,
                     dense1_kernel, dense1_bias, out_kernel, resh, wt);
  hipLaunchKernelGGL(moon_outgemm, dim3(PAIRS / 16 * 2), dim3(256), 0, stream,
                     resh, wt, out_bias, out);
}

// Round 8
// 124.222 us; speedup vs baseline: 1.5714x; 1.0029x over previous
//
#include <hip/hip_runtime.h>
#include <hip/hip_bf16.h>

constexpr int NB   = 32;
constexpr int NENV = 8;
constexpr int F0   = 16;
constexpr int F1   = 32;
constexpr int D    = 256;
constexpr int PAIRS = 128 * 64;   // 8192
constexpr float CUT = 5.0f;
constexpr int WT_STRIDE = 264;    // ushorts per row of Wt (16B aligned, breaks 512B aliasing)

typedef float f32x4 __attribute__((ext_vector_type(4)));
typedef short s16x8 __attribute__((ext_vector_type(8)));

__device__ __forceinline__ float fast_rcp(float x) { return __builtin_amdgcn_rcpf(x); }
__device__ __forceinline__ float silu(float a) {
  return a * fast_rcp(1.0f + __expf(-a));
}
__device__ __forceinline__ float fast_tanh(float t) {
  return 1.0f - 2.0f * fast_rcp(__expf(2.0f * t) + 1.0f);
}
__device__ __forceinline__ unsigned short f2bf(float f) {
  __hip_bfloat16 h = __float2bfloat16(f);
  unsigned short u; __builtin_memcpy(&u, &h, 2); return u;
}

// ---------------------------------------------------------------------------
// Prep kernel: out_kernel (fp32 [k][d]) -> wt (bf16 [d][k], stride WT_STRIDE).
// Must be a separate launch: ALL fused blocks consume wt (no intra-kernel
// producer/consumer ordering exists across blocks).
// ---------------------------------------------------------------------------
__global__ __launch_bounds__(256) void moon_prep(
    const float* __restrict__ out_kernel,   // [256,256]
    unsigned short* __restrict__ wt)        // [256, WT_STRIDE] bf16 (W^T)
{
  const int i  = blockIdx.x * 256 + threadIdx.x;  // [0, 16384)
  const int d  = i >> 6;                   // 0..255
  const int kg = i & 63;                   // 0..63
  ushort4 p;
  p.x = f2bf(out_kernel[(4 * kg + 0) * D + d]);
  p.y = f2bf(out_kernel[(4 * kg + 1) * D + d]);
  p.z = f2bf(out_kernel[(4 * kg + 2) * D + d]);
  p.w = f2bf(out_kernel[(4 * kg + 3) * D + d]);
  *(ushort4*)&wt[d * WT_STRIDE + 4 * kg] = p;
}

// ---------------------------------------------------------------------------
// Fused kernel: phases 1-2 (one wave per (b,e) pair, validated r7 structure)
// + out-GEMM tail per block (validated outgemm fragment recipe).
// res never touches global memory: bf16 via block LDS (s_resall).
// ---------------------------------------------------------------------------
__global__ __launch_bounds__(256)
__attribute__((amdgpu_waves_per_eu(4, 4)))
void moon_fused(
    const float* __restrict__ r,            // [8192,3]
    const float* __restrict__ r_nb,         // [8192,32,3]
    const float* __restrict__ ee_scales,    // [8]
    const float* __restrict__ ee_kernel,    // [4,16]
    const float* __restrict__ ee_bias,      // [16]
    const float* __restrict__ beta_kernel,  // [24,32]
    const float* __restrict__ beta_bias,    // [32]
    const float* __restrict__ gamma_kernel, // [32,256]
    const float* __restrict__ dense1_kernel,// [4,256]
    const float* __restrict__ dense1_bias,  // [256]
    const unsigned short* __restrict__ wt,  // [256, WT_STRIDE] bf16 (W^T, from prep)
    const float* __restrict__ out_bias,     // [256]
    float* __restrict__ out)                // [8192,256]
{
  __shared__ float s_eek[4 * F0];
  __shared__ float s_eeb[F0];
  __shared__ float s_bk[(F0 + NENV) * F1];          // 768
  __shared__ float s_bb[F1];
  __shared__ float s_is2[NENV];
  __shared__ unsigned short s_ghT[4][D * 8];        // [kslot g][d][8] bf16 (16 KB)
  __shared__ unsigned short s_d1kT[D * 8];          // [d][8] bf16 x0.25: rows 0..3, bias at k=4 (4 KB)
  __shared__ unsigned short s_betah[4][4][NB * 8];  // [wave][g][n][8] bf16 (8 KB)
  __shared__ unsigned short s_inph[4][NB * 8];      // [wave][n][8] bf16 A-frag (2 KB)
  __shared__ unsigned short s_resall[4 * 264];      // [pair][264] bf16 res rows (2.1 KB)

  const int tid = threadIdx.x;
  const int w   = tid >> 6;
  const int l   = tid & 63;
  const int be  = blockIdx.x * 4 + w;
  const int be0 = blockIdx.x * 4;

  // ---- staging: small weights ----
  for (int i = tid; i < 888; i += 256) {
    if (i < 64)        s_eek[i]       = ee_kernel[i];
    else if (i < 80)   s_eeb[i - 64]  = ee_bias[i - 64];
    else if (i < 848)  s_bk[i - 80]   = beta_kernel[i - 80];
    else if (i < 880)  s_bb[i - 848]  = beta_bias[i - 848];
    else { float s = ee_scales[i - 880]; s_is2[i - 880] = 1.0f / (s * s); }
  }
  // ---- staging: gamma -> bf16 transposed, k-chunked (thread t owns row d=t) ----
  {
    const int d = tid;
    unsigned int pk[16];
    #pragma unroll
    for (int k2 = 0; k2 < 16; ++k2) {
      unsigned short lo = f2bf(gamma_kernel[(2 * k2 + 0) * D + d]);
      unsigned short hi = f2bf(gamma_kernel[(2 * k2 + 1) * D + d]);
      pk[k2] = (unsigned int)lo | ((unsigned int)hi << 16);
    }
    #pragma unroll
    for (int g = 0; g < 4; ++g)
      *(uint4*)&s_ghT[g][d * 8] = make_uint4(pk[4*g], pk[4*g+1], pk[4*g+2], pk[4*g+3]);
  }
  // ---- staging: d1kT b-frag, PRE-SCALED by 0.25 (replication cancel; exact) ----
  {
    const int d = tid;
    unsigned int p0 = (unsigned int)f2bf(0.25f * dense1_kernel[0 * D + d])
                    | ((unsigned int)f2bf(0.25f * dense1_kernel[1 * D + d]) << 16);
    unsigned int p1 = (unsigned int)f2bf(0.25f * dense1_kernel[2 * D + d])
                    | ((unsigned int)f2bf(0.25f * dense1_kernel[3 * D + d]) << 16);
    unsigned int p2 = (unsigned int)f2bf(0.25f * dense1_bias[d]);  // k=4; k=5..7 zero
    *(uint4*)&s_d1kT[d * 8] = make_uint4(p0, p1, p2, 0u);
  }

  __syncthreads();

  // ---- phase 1: pairwise filter -> s_betah[w] (bf16), s_inph[w] (bf16 A-frag) ----
  {
    const int n  = l & 31;
    const int cg = l >> 5;
    float rx = r[be * 3 + 0];
    float ry = r[be * 3 + 1];
    float rz = r[be * 3 + 2];
    const float* rn = r_nb + (be * NB + n) * 3;
    float dx = rn[0] - rx;
    float dy = rn[1] - ry;
    float dz = rn[2] - rz;
    float d2 = dx * dx + dy * dy + dz * dz;
    float dist = sqrtf(d2);
    float feats[4] = {dist, dx, dy, dz};
    float h[F0];
    #pragma unroll
    for (int j = 0; j < F0; ++j) {
      float t = s_eeb[j];
      #pragma unroll
      for (int i = 0; i < 4; ++i) t += feats[i] * s_eek[i * F0 + j];
      h[j] = fast_tanh(t);
    }
    float env[NENV];
    #pragma unroll
    for (int s = 0; s < NENV; ++s) env[s] = __expf(-d2 * s_is2[s]);
    float xc = dist * (1.0f / CUT);
    float fcut = (xc < 1.0f)
               ? 0.5f * (__cosf(3.14159265358979323846f * xc) + 1.0f)
               : 0.0f;
    if (cg == 0) {
      float lp = log1pf(dist);
      float inv = lp / dist;
      // A-frag k-slots: lp, dx', dy', dz', 1.0(bias), 0,0,0
      unsigned int q0 = (unsigned int)f2bf(lp) | ((unsigned int)f2bf(dx * inv) << 16);
      unsigned int q1 = (unsigned int)f2bf(dy * inv) | ((unsigned int)f2bf(dz * inv) << 16);
      *(uint4*)&s_inph[w][n * 8] = make_uint4(q0, q1, 0x3F80u /*bf16 1.0 at k=4*/, 0u);
    }
    unsigned int pk[8];
    #pragma unroll
    for (int c4 = 0; c4 < 4; ++c4) {
      float bb[4];
      #pragma unroll
      for (int cc = 0; cc < 4; ++cc) {
        int c = cg * 16 + c4 * 4 + cc;
        float a = s_bb[c];
        #pragma unroll
        for (int k = 0; k < F0; ++k) a += h[k] * s_bk[k * F1 + c];
        #pragma unroll
        for (int s = 0; s < NENV; ++s) a += env[s] * s_bk[(F0 + s) * F1 + c];
        bb[cc] = a * fcut;
      }
      pk[c4 * 2 + 0] = (unsigned int)f2bf(bb[0]) | ((unsigned int)f2bf(bb[1]) << 16);
      pk[c4 * 2 + 1] = (unsigned int)f2bf(bb[2]) | ((unsigned int)f2bf(bb[3]) << 16);
    }
    *(uint4*)&s_betah[w][2 * cg + 0][n * 8] = make_uint4(pk[0], pk[1], pk[2], pk[3]);
    *(uint4*)&s_betah[w][2 * cg + 1][n * 8] = make_uint4(pk[4], pk[5], pk[6], pk[7]);
  }
  __syncthreads();

  // ---- phase 2: per d-tile: c = beta@G (MFMA), f = inp@d1k+b (MFMA, replicated),
  //      res_d = sum_n silu(f)*c via shfl-reduce -> s_resall[pair w] as bf16 ----
  const int li = l & 15;          // d-within-tile / m-within-tile
  const int g  = l >> 4;          // k-slot group (and C row group)

  s16x8 a0 = *(const s16x8*)&s_betah[w][g][(0 * 16 + li) * 8];
  s16x8 a1 = *(const s16x8*)&s_betah[w][g][(1 * 16 + li) * 8];
  // replicated inp A-frags: same data for every g (plain broadcast LDS reads)
  s16x8 ai0 = *(const s16x8*)&s_inph[w][(0 * 16 + li) * 8];
  s16x8 ai1 = *(const s16x8*)&s_inph[w][(1 * 16 + li) * 8];

  #pragma unroll 4
  for (int nt = 0; nt < 16; ++nt) {
    const int d = nt * 16 + li;
    s16x8 b  = *(const s16x8*)&s_ghT[g][d * 8];
    s16x8 bd = *(const s16x8*)&s_d1kT[d * 8];    // replicated across g (x0.25 pre-scaled)
    f32x4 z = {0.f, 0.f, 0.f, 0.f};
    f32x4 c0 = __builtin_amdgcn_mfma_f32_16x16x32_bf16(a0, b, z, 0, 0, 0);
    f32x4 c1 = __builtin_amdgcn_mfma_f32_16x16x32_bf16(a1, b, z, 0, 0, 0);
    f32x4 f0 = __builtin_amdgcn_mfma_f32_16x16x32_bf16(ai0, bd, z, 0, 0, 0);
    f32x4 f1 = __builtin_amdgcn_mfma_f32_16x16x32_bf16(ai1, bd, z, 0, 0, 0);
    float p = 0.f;
    #pragma unroll
    for (int reg = 0; reg < 4; ++reg) {
      p += silu(f0[reg]) * c0[reg];
      p += silu(f1[reg]) * c1[reg];
    }
    // reduce over n (row groups live on lane bits 4..5)
    p += __shfl_xor(p, 16);
    p += __shfl_xor(p, 32);
    if (g == (nt & 3)) s_resall[w * 264 + nt * 16 + li] = f2bf(p);
  }
  __syncthreads();   // all 4 pairs' res rows needed by every wave in the tail

  // ---- tail: out[be0+0..3, :] = silu(res @ W + b). Wave w covers cols
  //      [w*64, w*64+64) (4 n-tiles). A rows = pairs replicated x4 (li&3);
  //      D rows m and m&3 identical, so only g==0 stores (rows 0..3). ----
  {
    const int col0 = w * 64;
    float bi[4];
    #pragma unroll
    for (int nt = 0; nt < 4; ++nt) bi[nt] = out_bias[col0 + nt * 16 + li];

    f32x4 acc[4] = {{0.f,0.f,0.f,0.f},{0.f,0.f,0.f,0.f},{0.f,0.f,0.f,0.f},{0.f,0.f,0.f,0.f}};
    const unsigned short* arow = &s_resall[(li & 3) * 264 + g * 8];
    const unsigned short* bp   = wt + (col0 + li) * WT_STRIDE + g * 8;

    #pragma unroll
    for (int ks = 0; ks < 8; ++ks) {
      s16x8 a = *(const s16x8*)(arow + ks * 32);
      #pragma unroll
      for (int nt = 0; nt < 4; ++nt) {
        s16x8 b = *(const s16x8*)(bp + nt * 16 * WT_STRIDE + ks * 32);
        acc[nt] = __builtin_amdgcn_mfma_f32_16x16x32_bf16(a, b, acc[nt], 0, 0, 0);
      }
    }
    if (g == 0) {
      #pragma unroll
      for (int nt = 0; nt < 4; ++nt) {
        #pragma unroll
        for (int reg = 0; reg < 4; ++reg) {
          out[(be0 + reg) * D + col0 + nt * 16 + li] = silu(acc[nt][reg] + bi[nt]);
        }
      }
    }
  }
}

extern "C" void kernel_launch(void* const* d_in, const int* in_sizes, int n_in,
                              void* d_out, int out_size, void* d_ws, size_t ws_size,
                              hipStream_t stream) {
  const float* r            = (const float*)d_in[0];
  const float* r_nb         = (const float*)d_in[1];
  const float* ee_scales    = (const float*)d_in[2];
  const float* ee_kernel    = (const float*)d_in[3];
  const float* ee_bias      = (const float*)d_in[4];
  const float* beta_kernel  = (const float*)d_in[5];
  const float* beta_bias    = (const float*)d_in[6];
  const float* gamma_kernel = (const float*)d_in[7];
  const float* dense1_kernel= (const float*)d_in[8];
  const float* dense1_bias  = (const float*)d_in[9];
  const float* out_kernel   = (const float*)d_in[10];
  const float* out_bias     = (const float*)d_in[11];
  float* out = (float*)d_out;

  unsigned short* wt = (unsigned short*)d_ws;   // 132 KB bf16 (W^T)

  hipLaunchKernelGGL(moon_prep, dim3(64), dim3(256), 0, stream, out_kernel, wt);
  hipLaunchKernelGGL(moon_fused, dim3(PAIRS / 4), dim3(256), 0, stream,
                     r, r_nb, ee_scales, ee_kernel, ee_bias,
                     beta_kernel, beta_bias, gamma_kernel,
                     dense1_kernel, dense1_bias, wt, out_bias, out);
}

// Round 9
// 117.278 us; speedup vs baseline: 1.6645x; 1.0592x over previous
//
#include <hip/hip_runtime.h>
#include <hip/hip_bf16.h>

constexpr int NB   = 32;
constexpr int NENV = 8;
constexpr int F0   = 16;
constexpr int F1   = 32;
constexpr int D    = 256;
constexpr int PAIRS = 128 * 64;   // 8192
constexpr float CUT = 5.0f;
constexpr int WT_STRIDE = 264;    // ushorts per row of Wt (16B aligned, breaks 512B aliasing)

typedef float f32x4 __attribute__((ext_vector_type(4)));
typedef short s16x8 __attribute__((ext_vector_type(8)));

__device__ __forceinline__ float fast_rcp(float x) { return __builtin_amdgcn_rcpf(x); }
__device__ __forceinline__ float silu(float a) {
  return a * fast_rcp(1.0f + __expf(-a));
}
__device__ __forceinline__ float fast_tanh(float t) {
  return 1.0f - 2.0f * fast_rcp(__expf(2.0f * t) + 1.0f);
}
// gfx950 single-instruction packed fp32->bf16 (RNE), replaces ~10-inst emulation
__device__ __forceinline__ unsigned int cvt_pk_bf16(float a, float b) {
  unsigned int r;
  asm("v_cvt_pk_bf16_f32 %0, %1, %2" : "=v"(r) : "v"(a), "v"(b));
  return r;
}
__device__ __forceinline__ unsigned short f2bf(float f) {
  return (unsigned short)(cvt_pk_bf16(f, f) & 0xffffu);
}

// ---------------------------------------------------------------------------
// Prep kernel: out_kernel (fp32 [k][d]) -> wt (bf16 [d][k], stride WT_STRIDE).
// ---------------------------------------------------------------------------
__global__ __launch_bounds__(256) void moon_prep(
    const float* __restrict__ out_kernel,   // [256,256]
    unsigned short* __restrict__ wt)        // [256, WT_STRIDE] bf16 (W^T)
{
  const int i  = blockIdx.x * 256 + threadIdx.x;  // [0, 16384)
  const int d  = i >> 6;                   // 0..255
  const int kg = i & 63;                   // 0..63
  unsigned int p0 = cvt_pk_bf16(out_kernel[(4 * kg + 0) * D + d],
                                out_kernel[(4 * kg + 1) * D + d]);
  unsigned int p1 = cvt_pk_bf16(out_kernel[(4 * kg + 2) * D + d],
                                out_kernel[(4 * kg + 3) * D + d]);
  *(uint2*)&wt[d * WT_STRIDE + 4 * kg] = make_uint2(p0, p1);
}

// ---------------------------------------------------------------------------
// Fused kernel. One wave per (b,e) pair; 4 pairs/block.
//   phase 1: per-neighbor features; lane-halves split the k-range (half0:
//            h[0..7]+inp-frag+bias-row, half1: h[8..15]+env+fcut) -- no
//            duplicated transcendentals.
//   beta:    beta = (hen @ beta_kernel + bias) * fcut via 4 MFMAs (K=25<=32,
//            bias at k=24); C-layout scattered back to A-frag layout in the
//            SAME LDS array (s_hb: hen-role then betah-role; same-array
//            dependencies keep compiler ordering honest).
//   phase 2: r7-validated dual-MFMA (beta@G and inp@d1k replicated x0.25).
//   tail:    r8-validated out-GEMM per block.
// ---------------------------------------------------------------------------
__global__ __launch_bounds__(256)
__attribute__((amdgpu_waves_per_eu(4, 4)))
void moon_fused(
    const float* __restrict__ r,            // [8192,3]
    const float* __restrict__ r_nb,         // [8192,32,3]
    const float* __restrict__ ee_scales,    // [8]
    const float* __restrict__ ee_kernel,    // [4,16]
    const float* __restrict__ ee_bias,      // [16]
    const float* __restrict__ beta_kernel,  // [24,32]
    const float* __restrict__ beta_bias,    // [32]
    const float* __restrict__ gamma_kernel, // [32,256]
    const float* __restrict__ dense1_kernel,// [4,256]
    const float* __restrict__ dense1_bias,  // [256]
    const unsigned short* __restrict__ wt,  // [256, WT_STRIDE] bf16 (W^T, from prep)
    const float* __restrict__ out_bias,     // [256]
    float* __restrict__ out)                // [8192,256]
{
  __shared__ float s_eek[4 * F0];
  __shared__ float s_eeb[F0];
  __shared__ float s_is2[NENV];
  __shared__ unsigned short s_ghT[4][D * 8];        // [kslot g][d][8] bf16 (16 KB)
  __shared__ unsigned short s_d1kT[D * 8];          // [d][8] bf16 x0.25 (4 KB)
  __shared__ unsigned short s_bkh[4][F1 * 8];       // B-frags of beta_kernel+bias (2 KB)
  __shared__ unsigned short s_hb[4][4][NB * 8];     // [wave][g][row][8]: hen then betah (8 KB)
  __shared__ unsigned short s_inph[4][NB * 8];      // [wave][n][8] bf16 inp A-frag (2 KB)
  __shared__ float s_fcut[4][NB];                   // (0.5 KB)
  __shared__ unsigned short s_resall[4 * 264];      // [pair][264] bf16 res rows (2.1 KB)

  const int tid = threadIdx.x;
  const int w   = tid >> 6;
  const int l   = tid & 63;
  const int be  = blockIdx.x * 4 + w;
  const int be0 = blockIdx.x * 4;

  // ---- staging: small weights ----
  if (tid < 64)       s_eek[tid]      = ee_kernel[tid];
  else if (tid < 80)  s_eeb[tid - 64] = ee_bias[tid - 64];
  else if (tid < 88) { float s = ee_scales[tid - 80]; s_is2[tid - 80] = 1.0f / (s * s); }

  // ---- staging: beta_kernel -> B-frags (k-chunks; bias row at k=24) ----
  if (tid < 128) {
    const int c = tid & 31;
    const int g = tid >> 5;
    unsigned int q[4];
    if (g < 3) {
      float v[8];
      #pragma unroll
      for (int j = 0; j < 8; ++j) v[j] = beta_kernel[(g * 8 + j) * F1 + c];
      q[0] = cvt_pk_bf16(v[0], v[1]); q[1] = cvt_pk_bf16(v[2], v[3]);
      q[2] = cvt_pk_bf16(v[4], v[5]); q[3] = cvt_pk_bf16(v[6], v[7]);
    } else {
      q[0] = cvt_pk_bf16(beta_bias[c], 0.0f); q[1] = 0; q[2] = 0; q[3] = 0;
    }
    *(uint4*)&s_bkh[g][c * 8] = make_uint4(q[0], q[1], q[2], q[3]);
  }

  // ---- staging: gamma -> bf16 transposed, k-chunked (thread t owns row d=t) ----
  {
    const int d = tid;
    unsigned int pk[16];
    #pragma unroll
    for (int k2 = 0; k2 < 16; ++k2)
      pk[k2] = cvt_pk_bf16(gamma_kernel[(2 * k2 + 0) * D + d],
                           gamma_kernel[(2 * k2 + 1) * D + d]);
    #pragma unroll
    for (int g = 0; g < 4; ++g)
      *(uint4*)&s_ghT[g][d * 8] = make_uint4(pk[4*g], pk[4*g+1], pk[4*g+2], pk[4*g+3]);
  }
  // ---- staging: d1kT b-frag, PRE-SCALED by 0.25 (replication cancel; exact) ----
  {
    const int d = tid;
    unsigned int p0 = cvt_pk_bf16(0.25f * dense1_kernel[0 * D + d],
                                  0.25f * dense1_kernel[1 * D + d]);
    unsigned int p1 = cvt_pk_bf16(0.25f * dense1_kernel[2 * D + d],
                                  0.25f * dense1_kernel[3 * D + d]);
    unsigned int p2 = cvt_pk_bf16(0.25f * dense1_bias[d], 0.0f);  // k=4; k=5..7 zero
    *(uint4*)&s_d1kT[d * 8] = make_uint4(p0, p1, p2, 0u);
  }

  __syncthreads();

  const int li = l & 15;          // col-within-tile
  const int g  = l >> 4;          // k-chunk / C-row group

  // ---- phase 1: per-neighbor features -> s_hb (hen role), s_inph, s_fcut ----
  {
    const int n    = l & 31;
    const int half = l >> 5;     // k-range split
    float rx = r[be * 3 + 0];
    float ry = r[be * 3 + 1];
    float rz = r[be * 3 + 2];
    const float* rn = r_nb + (be * NB + n) * 3;
    float dx = rn[0] - rx;
    float dy = rn[1] - ry;
    float dz = rn[2] - rz;
    float d2 = dx * dx + dy * dy + dz * dz;
    float dist = sqrtf(d2);
    float feats[4] = {dist, dx, dy, dz};
    float h[8];
    #pragma unroll
    for (int j8 = 0; j8 < 8; ++j8) {
      int j = half * 8 + j8;
      float t = s_eeb[j];
      #pragma unroll
      for (int i = 0; i < 4; ++i) t += feats[i] * s_eek[i * F0 + j];
      h[j8] = fast_tanh(t);
    }
    unsigned int hp0 = cvt_pk_bf16(h[0], h[1]);
    unsigned int hp1 = cvt_pk_bf16(h[2], h[3]);
    unsigned int hp2 = cvt_pk_bf16(h[4], h[5]);
    unsigned int hp3 = cvt_pk_bf16(h[6], h[7]);
    if (half == 0) {
      // hen chunk 0 = h[0..7]; chunk 3 = bias row (k24 = 1.0)
      *(uint4*)&s_hb[w][0][n * 8] = make_uint4(hp0, hp1, hp2, hp3);
      *(uint4*)&s_hb[w][3][n * 8] = make_uint4(0x3F80u, 0u, 0u, 0u);
      float lp  = log1pf(dist);
      float inv = lp / dist;
      unsigned int q0 = cvt_pk_bf16(lp, dx * inv);
      unsigned int q1 = cvt_pk_bf16(dy * inv, dz * inv);
      *(uint4*)&s_inph[w][n * 8] = make_uint4(q0, q1, 0x3F80u, 0u);
    } else {
      // hen chunk 1 = h[8..15]; chunk 2 = env[0..7]; fcut
      *(uint4*)&s_hb[w][1][n * 8] = make_uint4(hp0, hp1, hp2, hp3);
      float env[NENV];
      #pragma unroll
      for (int s = 0; s < NENV; ++s) env[s] = __expf(-d2 * s_is2[s]);
      unsigned int e0 = cvt_pk_bf16(env[0], env[1]);
      unsigned int e1 = cvt_pk_bf16(env[2], env[3]);
      unsigned int e2 = cvt_pk_bf16(env[4], env[5]);
      unsigned int e3 = cvt_pk_bf16(env[6], env[7]);
      *(uint4*)&s_hb[w][2][n * 8] = make_uint4(e0, e1, e2, e3);
      float xc = dist * (1.0f / CUT);
      s_fcut[w][n] = (xc < 1.0f)
                   ? 0.5f * (__cosf(3.14159265358979323846f * xc) + 1.0f)
                   : 0.0f;
    }
  }

  // ---- beta via MFMA: beta[n][c] = (hen @ bk + bias) * fcut[n] ----
  // (wave-local: same-wave LDS ops are in program order; s_hb same-array deps)
  {
    s16x8 ah0 = *(const s16x8*)&s_hb[w][g][(0 * 16 + li) * 8];
    s16x8 ah1 = *(const s16x8*)&s_hb[w][g][(1 * 16 + li) * 8];
    s16x8 bb0 = *(const s16x8*)&s_bkh[g][(0 * 16 + li) * 8];
    s16x8 bb1 = *(const s16x8*)&s_bkh[g][(1 * 16 + li) * 8];
    f32x4 z = {0.f, 0.f, 0.f, 0.f};
    f32x4 c00 = __builtin_amdgcn_mfma_f32_16x16x32_bf16(ah0, bb0, z, 0, 0, 0);
    f32x4 c01 = __builtin_amdgcn_mfma_f32_16x16x32_bf16(ah0, bb1, z, 0, 0, 0);
    f32x4 c10 = __builtin_amdgcn_mfma_f32_16x16x32_bf16(ah1, bb0, z, 0, 0, 0);
    f32x4 c11 = __builtin_amdgcn_mfma_f32_16x16x32_bf16(ah1, bb1, z, 0, 0, 0);
    const int cl = li >> 3;       // chunk for cols 0..15 -> {0,1}
    const int sl = li & 7;        // slot within chunk
    #pragma unroll
    for (int reg = 0; reg < 4; ++reg) {
      int row0 = g * 4 + reg;
      int row1 = 16 + g * 4 + reg;
      float fc0 = s_fcut[w][row0];
      float fc1 = s_fcut[w][row1];
      s_hb[w][cl    ][row0 * 8 + sl] = f2bf(c00[reg] * fc0);  // cols 0..15
      s_hb[w][2 + cl][row0 * 8 + sl] = f2bf(c01[reg] * fc0);  // cols 16..31
      s_hb[w][cl    ][row1 * 8 + sl] = f2bf(c10[reg] * fc1);
      s_hb[w][2 + cl][row1 * 8 + sl] = f2bf(c11[reg] * fc1);
    }
  }

  // ---- phase 2: per d-tile: c = beta@G, f = inp@d1k+b (replicated x0.25),
  //      res_d = sum_n silu(f)*c via shfl-reduce -> s_resall bf16 ----
  s16x8 a0 = *(const s16x8*)&s_hb[w][g][(0 * 16 + li) * 8];   // betah role
  s16x8 a1 = *(const s16x8*)&s_hb[w][g][(1 * 16 + li) * 8];
  s16x8 ai0 = *(const s16x8*)&s_inph[w][(0 * 16 + li) * 8];
  s16x8 ai1 = *(const s16x8*)&s_inph[w][(1 * 16 + li) * 8];

  #pragma unroll 4
  for (int nt = 0; nt < 16; ++nt) {
    const int d = nt * 16 + li;
    s16x8 b  = *(const s16x8*)&s_ghT[g][d * 8];
    s16x8 bd = *(const s16x8*)&s_d1kT[d * 8];
    f32x4 z = {0.f, 0.f, 0.f, 0.f};
    f32x4 c0 = __builtin_amdgcn_mfma_f32_16x16x32_bf16(a0, b, z, 0, 0, 0);
    f32x4 c1 = __builtin_amdgcn_mfma_f32_16x16x32_bf16(a1, b, z, 0, 0, 0);
    f32x4 f0 = __builtin_amdgcn_mfma_f32_16x16x32_bf16(ai0, bd, z, 0, 0, 0);
    f32x4 f1 = __builtin_amdgcn_mfma_f32_16x16x32_bf16(ai1, bd, z, 0, 0, 0);
    float p = 0.f;
    #pragma unroll
    for (int reg = 0; reg < 4; ++reg) {
      p += silu(f0[reg]) * c0[reg];
      p += silu(f1[reg]) * c1[reg];
    }
    p += __shfl_xor(p, 16);
    p += __shfl_xor(p, 32);
    if (g == (nt & 3)) s_resall[w * 264 + nt * 16 + li] = f2bf(p);
  }
  __syncthreads();   // all 4 pairs' res rows needed by every wave in the tail

  // ---- tail: out[be0+0..3, :] = silu(res @ W + b) (r8-validated) ----
  {
    const int col0 = w * 64;
    float bi[4];
    #pragma unroll
    for (int nt = 0; nt < 4; ++nt) bi[nt] = out_bias[col0 + nt * 16 + li];

    f32x4 acc[4] = {{0.f,0.f,0.f,0.f},{0.f,0.f,0.f,0.f},{0.f,0.f,0.f,0.f},{0.f,0.f,0.f,0.f}};
    const unsigned short* arow = &s_resall[(li & 3) * 264 + g * 8];
    const unsigned short* bp   = wt + (col0 + li) * WT_STRIDE + g * 8;

    #pragma unroll
    for (int ks = 0; ks < 8; ++ks) {
      s16x8 a = *(const s16x8*)(arow + ks * 32);
      #pragma unroll
      for (int nt = 0; nt < 4; ++nt) {
        s16x8 b = *(const s16x8*)(bp + nt * 16 * WT_STRIDE + ks * 32);
        acc[nt] = __builtin_amdgcn_mfma_f32_16x16x32_bf16(a, b, acc[nt], 0, 0, 0);
      }
    }
    if (g == 0) {
      #pragma unroll
      for (int nt = 0; nt < 4; ++nt) {
        #pragma unroll
        for (int reg = 0; reg < 4; ++reg) {
          out[(be0 + reg) * D + col0 + nt * 16 + li] = silu(acc[nt][reg] + bi[nt]);
        }
      }
    }
  }
}

extern "C" void kernel_launch(void* const* d_in, const int* in_sizes, int n_in,
                              void* d_out, int out_size, void* d_ws, size_t ws_size,
                              hipStream_t stream) {
  const float* r            = (const float*)d_in[0];
  const float* r_nb         = (const float*)d_in[1];
  const float* ee_scales    = (const float*)d_in[2];
  const float* ee_kernel    = (const float*)d_in[3];
  const float* ee_bias      = (const float*)d_in[4];
  const float* beta_kernel  = (const float*)d_in[5];
  const float* beta_bias    = (const float*)d_in[6];
  const float* gamma_kernel = (const float*)d_in[7];
  const float* dense1_kernel= (const float*)d_in[8];
  const float* dense1_bias  = (const float*)d_in[9];
  const float* out_kernel   = (const float*)d_in[10];
  const float* out_bias     = (const float*)d_in[11];
  float* out = (float*)d_out;

  unsigned short* wt = (unsigned short*)d_ws;   // 132 KB bf16 (W^T)

  hipLaunchKernelGGL(moon_prep, dim3(64), dim3(256), 0, stream, out_kernel, wt);
  hipLaunchKernelGGL(moon_fused, dim3(PAIRS / 4), dim3(256), 0, stream,
                     r, r_nb, ee_scales, ee_kernel, ee_bias,
                     beta_kernel, beta_bias, gamma_kernel,
                     dense1_kernel, dense1_bias, wt, out_bias, out);
}

// Round 11
// 117.257 us; speedup vs baseline: 1.6648x; 1.0002x over previous
//
#include <hip/hip_runtime.h>
#include <hip/hip_bf16.h>

constexpr int NB   = 32;
constexpr int NENV = 8;
constexpr int F0   = 16;
constexpr int F1   = 32;
constexpr int D    = 256;
constexpr int PAIRS = 128 * 64;   // 8192
constexpr float CUT = 5.0f;
constexpr int WT_STRIDE = 264;    // ushorts per row of Wt (16B aligned, breaks 512B aliasing)

typedef float f32x4 __attribute__((ext_vector_type(4)));
typedef short s16x8 __attribute__((ext_vector_type(8)));

__device__ __forceinline__ float fast_rcp(float x) { return __builtin_amdgcn_rcpf(x); }
__device__ __forceinline__ float silu(float a) {
  return a * fast_rcp(1.0f + __expf(-a));
}
__device__ __forceinline__ float fast_tanh(float t) {
  return 1.0f - 2.0f * fast_rcp(__expf(2.0f * t) + 1.0f);
}
// gfx950 single-instruction packed fp32->bf16 (RNE)
__device__ __forceinline__ unsigned int cvt_pk_bf16(float a, float b) {
  unsigned int r;
  asm("v_cvt_pk_bf16_f32 %0, %1, %2" : "=v"(r) : "v"(a), "v"(b));
  return r;
}
__device__ __forceinline__ unsigned short f2bf(float f) {
  return (unsigned short)(cvt_pk_bf16(f, f) & 0xffffu);
}

// ---------------------------------------------------------------------------
// Prep kernel: out_kernel (fp32 [k][d]) -> wt (bf16 [d][k], stride WT_STRIDE).
// READ-coalesced mapping (r10 improvement kept): i = kg*256 + d, lanes sweep d
// -> coalesced dword loads; scattered 8B stores are fire-and-forget.
// ---------------------------------------------------------------------------
__global__ __launch_bounds__(256) void moon_prep(
    const float* __restrict__ out_kernel,   // [256,256]
    unsigned short* __restrict__ wt)        // [256, WT_STRIDE] bf16 (W^T)
{
  const int i  = blockIdx.x * 256 + threadIdx.x;  // [0, 16384)
  const int d  = i & 255;                  // fastest -> coalesced reads
  const int kg = i >> 8;                   // 0..63
  unsigned int p0 = cvt_pk_bf16(out_kernel[(4 * kg + 0) * D + d],
                                out_kernel[(4 * kg + 1) * D + d]);
  unsigned int p1 = cvt_pk_bf16(out_kernel[(4 * kg + 2) * D + d],
                                out_kernel[(4 * kg + 3) * D + d]);
  *(uint2*)&wt[d * WT_STRIDE + 4 * kg] = make_uint2(p0, p1);
}

// ---------------------------------------------------------------------------
// Fused kernel (r9-validated, byte-identical body). One wave per (b,e) pair.
//   phase 1: per-neighbor features; lane-halves split the k-range.
//   beta:    (hen @ beta_kernel + bias) * fcut via 4 MFMAs (bias at k=24).
//   phase 2: dual-MFMA (beta@G and inp@d1k replicated x0.25 pre-scale).
//   tail:    out-GEMM per block from LDS res rows.
// ---------------------------------------------------------------------------
__global__ __launch_bounds__(256)
__attribute__((amdgpu_waves_per_eu(4, 4)))
void moon_fused(
    const float* __restrict__ r,            // [8192,3]
    const float* __restrict__ r_nb,         // [8192,32,3]
    const float* __restrict__ ee_scales,    // [8]
    const float* __restrict__ ee_kernel,    // [4,16]
    const float* __restrict__ ee_bias,      // [16]
    const float* __restrict__ beta_kernel,  // [24,32]
    const float* __restrict__ beta_bias,    // [32]
    const float* __restrict__ gamma_kernel, // [32,256]
    const float* __restrict__ dense1_kernel,// [4,256]
    const float* __restrict__ dense1_bias,  // [256]
    const unsigned short* __restrict__ wt,  // [256, WT_STRIDE] bf16 (W^T, from prep)
    const float* __restrict__ out_bias,     // [256]
    float* __restrict__ out)                // [8192,256]
{
  __shared__ float s_eek[4 * F0];
  __shared__ float s_eeb[F0];
  __shared__ float s_is2[NENV];
  __shared__ unsigned short s_ghT[4][D * 8];        // [kslot g][d][8] bf16 (16 KB)
  __shared__ unsigned short s_d1kT[D * 8];          // [d][8] bf16 x0.25 (4 KB)
  __shared__ unsigned short s_bkh[4][F1 * 8];       // B-frags of beta_kernel+bias (2 KB)
  __shared__ unsigned short s_hb[4][4][NB * 8];     // [wave][g][row][8]: hen then betah (8 KB)
  __shared__ unsigned short s_inph[4][NB * 8];      // [wave][n][8] bf16 inp A-frag (2 KB)
  __shared__ float s_fcut[4][NB];                   // (0.5 KB)
  __shared__ unsigned short s_resall[4 * 264];      // [pair][264] bf16 res rows (2.1 KB)

  const int tid = threadIdx.x;
  const int w   = tid >> 6;
  const int l   = tid & 63;
  const int be  = blockIdx.x * 4 + w;
  const int be0 = blockIdx.x * 4;

  // ---- staging: small weights ----
  if (tid < 64)       s_eek[tid]      = ee_kernel[tid];
  else if (tid < 80)  s_eeb[tid - 64] = ee_bias[tid - 64];
  else if (tid < 88) { float s = ee_scales[tid - 80]; s_is2[tid - 80] = 1.0f / (s * s); }

  // ---- staging: beta_kernel -> B-frags (k-chunks; bias row at k=24) ----
  if (tid < 128) {
    const int c = tid & 31;
    const int g = tid >> 5;
    unsigned int q[4];
    if (g < 3) {
      float v[8];
      #pragma unroll
      for (int j = 0; j < 8; ++j) v[j] = beta_kernel[(g * 8 + j) * F1 + c];
      q[0] = cvt_pk_bf16(v[0], v[1]); q[1] = cvt_pk_bf16(v[2], v[3]);
      q[2] = cvt_pk_bf16(v[4], v[5]); q[3] = cvt_pk_bf16(v[6], v[7]);
    } else {
      q[0] = cvt_pk_bf16(beta_bias[c], 0.0f); q[1] = 0; q[2] = 0; q[3] = 0;
    }
    *(uint4*)&s_bkh[g][c * 8] = make_uint4(q[0], q[1], q[2], q[3]);
  }

  // ---- staging: gamma -> bf16 transposed, k-chunked (thread t owns row d=t) ----
  {
    const int d = tid;
    unsigned int pk[16];
    #pragma unroll
    for (int k2 = 0; k2 < 16; ++k2)
      pk[k2] = cvt_pk_bf16(gamma_kernel[(2 * k2 + 0) * D + d],
                           gamma_kernel[(2 * k2 + 1) * D + d]);
    #pragma unroll
    for (int g = 0; g < 4; ++g)
      *(uint4*)&s_ghT[g][d * 8] = make_uint4(pk[4*g], pk[4*g+1], pk[4*g+2], pk[4*g+3]);
  }
  // ---- staging: d1kT b-frag, PRE-SCALED by 0.25 (replication cancel; exact) ----
  {
    const int d = tid;
    unsigned int p0 = cvt_pk_bf16(0.25f * dense1_kernel[0 * D + d],
                                  0.25f * dense1_kernel[1 * D + d]);
    unsigned int p1 = cvt_pk_bf16(0.25f * dense1_kernel[2 * D + d],
                                  0.25f * dense1_kernel[3 * D + d]);
    unsigned int p2 = cvt_pk_bf16(0.25f * dense1_bias[d], 0.0f);  // k=4; k=5..7 zero
    *(uint4*)&s_d1kT[d * 8] = make_uint4(p0, p1, p2, 0u);
  }

  __syncthreads();

  const int li = l & 15;          // col-within-tile
  const int g  = l >> 4;          // k-chunk / C-row group

  // ---- phase 1: per-neighbor features -> s_hb (hen role), s_inph, s_fcut ----
  {
    const int n    = l & 31;
    const int half = l >> 5;     // k-range split
    float rx = r[be * 3 + 0];
    float ry = r[be * 3 + 1];
    float rz = r[be * 3 + 2];
    const float* rn = r_nb + (be * NB + n) * 3;
    float dx = rn[0] - rx;
    float dy = rn[1] - ry;
    float dz = rn[2] - rz;
    float d2 = dx * dx + dy * dy + dz * dz;
    float dist = sqrtf(d2);
    float feats[4] = {dist, dx, dy, dz};
    float h[8];
    #pragma unroll
    for (int j8 = 0; j8 < 8; ++j8) {
      int j = half * 8 + j8;
      float t = s_eeb[j];
      #pragma unroll
      for (int i = 0; i < 4; ++i) t += feats[i] * s_eek[i * F0 + j];
      h[j8] = fast_tanh(t);
    }
    unsigned int hp0 = cvt_pk_bf16(h[0], h[1]);
    unsigned int hp1 = cvt_pk_bf16(h[2], h[3]);
    unsigned int hp2 = cvt_pk_bf16(h[4], h[5]);
    unsigned int hp3 = cvt_pk_bf16(h[6], h[7]);
    if (half == 0) {
      *(uint4*)&s_hb[w][0][n * 8] = make_uint4(hp0, hp1, hp2, hp3);
      *(uint4*)&s_hb[w][3][n * 8] = make_uint4(0x3F80u, 0u, 0u, 0u);
      float lp  = log1pf(dist);
      float inv = lp / dist;
      unsigned int q0 = cvt_pk_bf16(lp, dx * inv);
      unsigned int q1 = cvt_pk_bf16(dy * inv, dz * inv);
      *(uint4*)&s_inph[w][n * 8] = make_uint4(q0, q1, 0x3F80u, 0u);
    } else {
      *(uint4*)&s_hb[w][1][n * 8] = make_uint4(hp0, hp1, hp2, hp3);
      float env[NENV];
      #pragma unroll
      for (int s = 0; s < NENV; ++s) env[s] = __expf(-d2 * s_is2[s]);
      unsigned int e0 = cvt_pk_bf16(env[0], env[1]);
      unsigned int e1 = cvt_pk_bf16(env[2], env[3]);
      unsigned int e2 = cvt_pk_bf16(env[4], env[5]);
      unsigned int e3 = cvt_pk_bf16(env[6], env[7]);
      *(uint4*)&s_hb[w][2][n * 8] = make_uint4(e0, e1, e2, e3);
      float xc = dist * (1.0f / CUT);
      s_fcut[w][n] = (xc < 1.0f)
                   ? 0.5f * (__cosf(3.14159265358979323846f * xc) + 1.0f)
                   : 0.0f;
    }
  }

  // ---- beta via MFMA: beta[n][c] = (hen @ bk + bias) * fcut[n] (wave-local) ----
  {
    s16x8 ah0 = *(const s16x8*)&s_hb[w][g][(0 * 16 + li) * 8];
    s16x8 ah1 = *(const s16x8*)&s_hb[w][g][(1 * 16 + li) * 8];
    s16x8 bb0 = *(const s16x8*)&s_bkh[g][(0 * 16 + li) * 8];
    s16x8 bb1 = *(const s16x8*)&s_bkh[g][(1 * 16 + li) * 8];
    f32x4 z = {0.f, 0.f, 0.f, 0.f};
    f32x4 c00 = __builtin_amdgcn_mfma_f32_16x16x32_bf16(ah0, bb0, z, 0, 0, 0);
    f32x4 c01 = __builtin_amdgcn_mfma_f32_16x16x32_bf16(ah0, bb1, z, 0, 0, 0);
    f32x4 c10 = __builtin_amdgcn_mfma_f32_16x16x32_bf16(ah1, bb0, z, 0, 0, 0);
    f32x4 c11 = __builtin_amdgcn_mfma_f32_16x16x32_bf16(ah1, bb1, z, 0, 0, 0);
    const int cl = li >> 3;
    const int sl = li & 7;
    #pragma unroll
    for (int reg = 0; reg < 4; ++reg) {
      int row0 = g * 4 + reg;
      int row1 = 16 + g * 4 + reg;
      float fc0 = s_fcut[w][row0];
      float fc1 = s_fcut[w][row1];
      s_hb[w][cl    ][row0 * 8 + sl] = f2bf(c00[reg] * fc0);
      s_hb[w][2 + cl][row0 * 8 + sl] = f2bf(c01[reg] * fc0);
      s_hb[w][cl    ][row1 * 8 + sl] = f2bf(c10[reg] * fc1);
      s_hb[w][2 + cl][row1 * 8 + sl] = f2bf(c11[reg] * fc1);
    }
  }

  // ---- phase 2: c = beta@G, f = inp@d1k+b (replicated x0.25); reduce ----
  {
    s16x8 a0 = *(const s16x8*)&s_hb[w][g][(0 * 16 + li) * 8];
    s16x8 a1 = *(const s16x8*)&s_hb[w][g][(1 * 16 + li) * 8];
    s16x8 ai0 = *(const s16x8*)&s_inph[w][(0 * 16 + li) * 8];
    s16x8 ai1 = *(const s16x8*)&s_inph[w][(1 * 16 + li) * 8];

    #pragma unroll 4
    for (int nt = 0; nt < 16; ++nt) {
      const int d = nt * 16 + li;
      s16x8 b  = *(const s16x8*)&s_ghT[g][d * 8];
      s16x8 bd = *(const s16x8*)&s_d1kT[d * 8];
      f32x4 z = {0.f, 0.f, 0.f, 0.f};
      f32x4 c0 = __builtin_amdgcn_mfma_f32_16x16x32_bf16(a0, b, z, 0, 0, 0);
      f32x4 c1 = __builtin_amdgcn_mfma_f32_16x16x32_bf16(a1, b, z, 0, 0, 0);
      f32x4 f0 = __builtin_amdgcn_mfma_f32_16x16x32_bf16(ai0, bd, z, 0, 0, 0);
      f32x4 f1 = __builtin_amdgcn_mfma_f32_16x16x32_bf16(ai1, bd, z, 0, 0, 0);
      float pv = 0.f;
      #pragma unroll
      for (int reg = 0; reg < 4; ++reg) {
        pv += silu(f0[reg]) * c0[reg];
        pv += silu(f1[reg]) * c1[reg];
      }
      pv += __shfl_xor(pv, 16);
      pv += __shfl_xor(pv, 32);
      if (g == (nt & 3)) s_resall[w * 264 + nt * 16 + li] = f2bf(pv);
    }
  }
  __syncthreads();   // all 4 pairs' res rows needed by every wave in the tail

  // ---- tail: out[be0+0..3, :] = silu(res @ W + b) ----
  {
    const int col0 = w * 64;
    float bi[4];
    #pragma unroll
    for (int nt = 0; nt < 4; ++nt) bi[nt] = out_bias[col0 + nt * 16 + li];

    f32x4 acc[4] = {{0.f,0.f,0.f,0.f},{0.f,0.f,0.f,0.f},{0.f,0.f,0.f,0.f},{0.f,0.f,0.f,0.f}};
    const unsigned short* arow = &s_resall[(li & 3) * 264 + g * 8];
    const unsigned short* bp   = wt + (col0 + li) * WT_STRIDE + g * 8;

    #pragma unroll
    for (int ks = 0; ks < 8; ++ks) {
      s16x8 a = *(const s16x8*)(arow + ks * 32);
      #pragma unroll
      for (int nt = 0; nt < 4; ++nt) {
        s16x8 b = *(const s16x8*)(bp + nt * 16 * WT_STRIDE + ks * 32);
        acc[nt] = __builtin_amdgcn_mfma_f32_16x16x32_bf16(a, b, acc[nt], 0, 0, 0);
      }
    }
    if (g == 0) {
      #pragma unroll
      for (int nt = 0; nt < 4; ++nt) {
        #pragma unroll
        for (int reg = 0; reg < 4; ++reg) {
          out[(be0 + reg) * D + col0 + nt * 16 + li] = silu(acc[nt][reg] + bi[nt]);
        }
      }
    }
  }
}

extern "C" void kernel_launch(void* const* d_in, const int* in_sizes, int n_in,
                              void* d_out, int out_size, void* d_ws, size_t ws_size,
                              hipStream_t stream) {
  const float* r            = (const float*)d_in[0];
  const float* r_nb         = (const float*)d_in[1];
  const float* ee_scales    = (const float*)d_in[2];
  const float* ee_kernel    = (const float*)d_in[3];
  const float* ee_bias      = (const float*)d_in[4];
  const float* beta_kernel  = (const float*)d_in[5];
  const float* beta_bias    = (const float*)d_in[6];
  const float* gamma_kernel = (const float*)d_in[7];
  const float* dense1_kernel= (const float*)d_in[8];
  const float* dense1_bias  = (const float*)d_in[9];
  const float* out_kernel   = (const float*)d_in[10];
  const float* out_bias     = (const float*)d_in[11];
  float* out = (float*)d_out;

  unsigned short* wt = (unsigned short*)d_ws;   // 132 KB bf16 (W^T)

  hipLaunchKernelGGL(moon_prep, dim3(64), dim3(256), 0, stream, out_kernel, wt);
  hipLaunchKernelGGL(moon_fused, dim3(PAIRS / 4), dim3(256), 0, stream,
                     r, r_nb, ee_scales, ee_kernel, ee_bias,
                     beta_kernel, beta_bias, gamma_kernel,
                     dense1_kernel, dense1_bias, wt, out_bias, out);
}

// Round 14
// 114.472 us; speedup vs baseline: 1.7053x; 1.0243x over previous
//
#include <hip/hip_runtime.h>
#include <hip/hip_bf16.h>

constexpr int NB   = 32;
constexpr int NENV = 8;
constexpr int F0   = 16;
constexpr int F1   = 32;
constexpr int D    = 256;
constexpr int PAIRS = 128 * 64;   // 8192
constexpr float CUT = 5.0f;

typedef float f32x4 __attribute__((ext_vector_type(4)));
typedef short s16x8 __attribute__((ext_vector_type(8)));

__device__ __forceinline__ float fast_rcp(float x) { return __builtin_amdgcn_rcpf(x); }
__device__ __forceinline__ float silu(float a) {
  return a * fast_rcp(1.0f + __expf(-a));
}
__device__ __forceinline__ float fast_tanh(float t) {
  return 1.0f - 2.0f * fast_rcp(__expf(2.0f * t) + 1.0f);
}
// gfx950 single-instruction packed fp32->bf16 (RNE)
__device__ __forceinline__ unsigned int cvt_pk_bf16(float a, float b) {
  unsigned int r;
  asm("v_cvt_pk_bf16_f32 %0, %1, %2" : "=v"(r) : "v"(a), "v"(b));
  return r;
}
__device__ __forceinline__ unsigned short f2bf(float f) {
  return (unsigned short)(cvt_pk_bf16(f, f) & 0xffffu);
}

// ---------------------------------------------------------------------------
// Single-dispatch fused kernel: r11-validated body, EXCEPT the tail builds its
// B-frags directly from fp32 out_kernel (bit-identical bf16 values to the old
// prep-kernel wt path) -- removes the prep launch + dispatch boundary.
// ---------------------------------------------------------------------------
__global__ __launch_bounds__(256)
__attribute__((amdgpu_waves_per_eu(4, 4)))
void moon_fused(
    const float* __restrict__ r,            // [8192,3]
    const float* __restrict__ r_nb,         // [8192,32,3]
    const float* __restrict__ ee_scales,    // [8]
    const float* __restrict__ ee_kernel,    // [4,16]
    const float* __restrict__ ee_bias,      // [16]
    const float* __restrict__ beta_kernel,  // [24,32]
    const float* __restrict__ beta_bias,    // [32]
    const float* __restrict__ gamma_kernel, // [32,256]
    const float* __restrict__ dense1_kernel,// [4,256]
    const float* __restrict__ dense1_bias,  // [256]
    const float* __restrict__ out_kernel,   // [256,256] (W[k][c], read in tail)
    const float* __restrict__ out_bias,     // [256]
    float* __restrict__ out)                // [8192,256]
{
  __shared__ float s_eek[4 * F0];
  __shared__ float s_eeb[F0];
  __shared__ float s_is2[NENV];
  __shared__ unsigned short s_ghT[4][D * 8];        // [kslot g][d][8] bf16 (16 KB)
  __shared__ unsigned short s_d1kT[D * 8];          // [d][8] bf16 x0.25 (4 KB)
  __shared__ unsigned short s_bkh[4][F1 * 8];       // B-frags of beta_kernel+bias (2 KB)
  __shared__ unsigned short s_hb[4][4][NB * 8];     // [wave][g][row][8]: hen then betah (8 KB)
  __shared__ unsigned short s_inph[4][NB * 8];      // [wave][n][8] bf16 inp A-frag (2 KB)
  __shared__ float s_fcut[4][NB];                   // (0.5 KB)
  __shared__ unsigned short s_resall[4 * 264];      // [pair][264] bf16 res rows (2.1 KB)

  const int tid = threadIdx.x;
  const int w   = tid >> 6;
  const int l   = tid & 63;
  const int be  = blockIdx.x * 4 + w;
  const int be0 = blockIdx.x * 4;

  // ---- staging: small weights ----
  if (tid < 64)       s_eek[tid]      = ee_kernel[tid];
  else if (tid < 80)  s_eeb[tid - 64] = ee_bias[tid - 64];
  else if (tid < 88) { float s = ee_scales[tid - 80]; s_is2[tid - 80] = 1.0f / (s * s); }

  // ---- staging: beta_kernel -> B-frags (k-chunks; bias row at k=24) ----
  if (tid < 128) {
    const int c = tid & 31;
    const int g = tid >> 5;
    unsigned int q[4];
    if (g < 3) {
      float v[8];
      #pragma unroll
      for (int j = 0; j < 8; ++j) v[j] = beta_kernel[(g * 8 + j) * F1 + c];
      q[0] = cvt_pk_bf16(v[0], v[1]); q[1] = cvt_pk_bf16(v[2], v[3]);
      q[2] = cvt_pk_bf16(v[4], v[5]); q[3] = cvt_pk_bf16(v[6], v[7]);
    } else {
      q[0] = cvt_pk_bf16(beta_bias[c], 0.0f); q[1] = 0; q[2] = 0; q[3] = 0;
    }
    *(uint4*)&s_bkh[g][c * 8] = make_uint4(q[0], q[1], q[2], q[3]);
  }

  // ---- staging: gamma -> bf16 transposed, k-chunked (thread t owns row d=t) ----
  {
    const int d = tid;
    unsigned int pk[16];
    #pragma unroll
    for (int k2 = 0; k2 < 16; ++k2)
      pk[k2] = cvt_pk_bf16(gamma_kernel[(2 * k2 + 0) * D + d],
                           gamma_kernel[(2 * k2 + 1) * D + d]);
    #pragma unroll
    for (int g = 0; g < 4; ++g)
      *(uint4*)&s_ghT[g][d * 8] = make_uint4(pk[4*g], pk[4*g+1], pk[4*g+2], pk[4*g+3]);
  }
  // ---- staging: d1kT b-frag, PRE-SCALED by 0.25 (replication cancel; exact) ----
  {
    const int d = tid;
    unsigned int p0 = cvt_pk_bf16(0.25f * dense1_kernel[0 * D + d],
                                  0.25f * dense1_kernel[1 * D + d]);
    unsigned int p1 = cvt_pk_bf16(0.25f * dense1_kernel[2 * D + d],
                                  0.25f * dense1_kernel[3 * D + d]);
    unsigned int p2 = cvt_pk_bf16(0.25f * dense1_bias[d], 0.0f);  // k=4; k=5..7 zero
    *(uint4*)&s_d1kT[d * 8] = make_uint4(p0, p1, p2, 0u);
  }

  __syncthreads();

  const int li = l & 15;          // col-within-tile
  const int g  = l >> 4;          // k-chunk / C-row group

  // ---- phase 1: per-neighbor features -> s_hb (hen role), s_inph, s_fcut ----
  {
    const int n    = l & 31;
    const int half = l >> 5;     // k-range split
    float rx = r[be * 3 + 0];
    float ry = r[be * 3 + 1];
    float rz = r[be * 3 + 2];
    const float* rn = r_nb + (be * NB + n) * 3;
    float dx = rn[0] - rx;
    float dy = rn[1] - ry;
    float dz = rn[2] - rz;
    float d2 = dx * dx + dy * dy + dz * dz;
    float dist = sqrtf(d2);
    float feats[4] = {dist, dx, dy, dz};
    float h[8];
    #pragma unroll
    for (int j8 = 0; j8 < 8; ++j8) {
      int j = half * 8 + j8;
      float t = s_eeb[j];
      #pragma unroll
      for (int i = 0; i < 4; ++i) t += feats[i] * s_eek[i * F0 + j];
      h[j8] = fast_tanh(t);
    }
    unsigned int hp0 = cvt_pk_bf16(h[0], h[1]);
    unsigned int hp1 = cvt_pk_bf16(h[2], h[3]);
    unsigned int hp2 = cvt_pk_bf16(h[4], h[5]);
    unsigned int hp3 = cvt_pk_bf16(h[6], h[7]);
    if (half == 0) {
      *(uint4*)&s_hb[w][0][n * 8] = make_uint4(hp0, hp1, hp2, hp3);
      *(uint4*)&s_hb[w][3][n * 8] = make_uint4(0x3F80u, 0u, 0u, 0u);
      float lp  = log1pf(dist);
      float inv = lp / dist;
      unsigned int q0 = cvt_pk_bf16(lp, dx * inv);
      unsigned int q1 = cvt_pk_bf16(dy * inv, dz * inv);
      *(uint4*)&s_inph[w][n * 8] = make_uint4(q0, q1, 0x3F80u, 0u);
    } else {
      *(uint4*)&s_hb[w][1][n * 8] = make_uint4(hp0, hp1, hp2, hp3);
      float env[NENV];
      #pragma unroll
      for (int s = 0; s < NENV; ++s) env[s] = __expf(-d2 * s_is2[s]);
      unsigned int e0 = cvt_pk_bf16(env[0], env[1]);
      unsigned int e1 = cvt_pk_bf16(env[2], env[3]);
      unsigned int e2 = cvt_pk_bf16(env[4], env[5]);
      unsigned int e3 = cvt_pk_bf16(env[6], env[7]);
      *(uint4*)&s_hb[w][2][n * 8] = make_uint4(e0, e1, e2, e3);
      float xc = dist * (1.0f / CUT);
      s_fcut[w][n] = (xc < 1.0f)
                   ? 0.5f * (__cosf(3.14159265358979323846f * xc) + 1.0f)
                   : 0.0f;
    }
  }

  // ---- beta via MFMA: beta[n][c] = (hen @ bk + bias) * fcut[n] (wave-local) ----
  {
    s16x8 ah0 = *(const s16x8*)&s_hb[w][g][(0 * 16 + li) * 8];
    s16x8 ah1 = *(const s16x8*)&s_hb[w][g][(1 * 16 + li) * 8];
    s16x8 bb0 = *(const s16x8*)&s_bkh[g][(0 * 16 + li) * 8];
    s16x8 bb1 = *(const s16x8*)&s_bkh[g][(1 * 16 + li) * 8];
    f32x4 z = {0.f, 0.f, 0.f, 0.f};
    f32x4 c00 = __builtin_amdgcn_mfma_f32_16x16x32_bf16(ah0, bb0, z, 0, 0, 0);
    f32x4 c01 = __builtin_amdgcn_mfma_f32_16x16x32_bf16(ah0, bb1, z, 0, 0, 0);
    f32x4 c10 = __builtin_amdgcn_mfma_f32_16x16x32_bf16(ah1, bb0, z, 0, 0, 0);
    f32x4 c11 = __builtin_amdgcn_mfma_f32_16x16x32_bf16(ah1, bb1, z, 0, 0, 0);
    const int cl = li >> 3;
    const int sl = li & 7;
    #pragma unroll
    for (int reg = 0; reg < 4; ++reg) {
      int row0 = g * 4 + reg;
      int row1 = 16 + g * 4 + reg;
      float fc0 = s_fcut[w][row0];
      float fc1 = s_fcut[w][row1];
      s_hb[w][cl    ][row0 * 8 + sl] = f2bf(c00[reg] * fc0);
      s_hb[w][2 + cl][row0 * 8 + sl] = f2bf(c01[reg] * fc0);
      s_hb[w][cl    ][row1 * 8 + sl] = f2bf(c10[reg] * fc1);
      s_hb[w][2 + cl][row1 * 8 + sl] = f2bf(c11[reg] * fc1);
    }
  }

  // ---- phase 2: c = beta@G, f = inp@d1k+b (replicated x0.25); reduce ----
  {
    s16x8 a0 = *(const s16x8*)&s_hb[w][g][(0 * 16 + li) * 8];
    s16x8 a1 = *(const s16x8*)&s_hb[w][g][(1 * 16 + li) * 8];
    s16x8 ai0 = *(const s16x8*)&s_inph[w][(0 * 16 + li) * 8];
    s16x8 ai1 = *(const s16x8*)&s_inph[w][(1 * 16 + li) * 8];

    #pragma unroll 4
    for (int nt = 0; nt < 16; ++nt) {
      const int d = nt * 16 + li;
      s16x8 b  = *(const s16x8*)&s_ghT[g][d * 8];
      s16x8 bd = *(const s16x8*)&s_d1kT[d * 8];
      f32x4 z = {0.f, 0.f, 0.f, 0.f};
      f32x4 c0 = __builtin_amdgcn_mfma_f32_16x16x32_bf16(a0, b, z, 0, 0, 0);
      f32x4 c1 = __builtin_amdgcn_mfma_f32_16x16x32_bf16(a1, b, z, 0, 0, 0);
      f32x4 f0 = __builtin_amdgcn_mfma_f32_16x16x32_bf16(ai0, bd, z, 0, 0, 0);
      f32x4 f1 = __builtin_amdgcn_mfma_f32_16x16x32_bf16(ai1, bd, z, 0, 0, 0);
      float pv = 0.f;
      #pragma unroll
      for (int reg = 0; reg < 4; ++reg) {
        pv += silu(f0[reg]) * c0[reg];
        pv += silu(f1[reg]) * c1[reg];
      }
      pv += __shfl_xor(pv, 16);
      pv += __shfl_xor(pv, 32);
      if (g == (nt & 3)) s_resall[w * 264 + nt * 16 + li] = f2bf(pv);
    }
  }
  __syncthreads();   // all 4 pairs' res rows needed by every wave in the tail

  // ---- tail: out[be0+0..3, :] = silu(res @ W + b). B-frags built directly
  //      from fp32 out_kernel: slot j of (ks,nt) = bf16(W[ks*32+g*8+j][c]),
  //      c = col0 + nt*16 + li. Bit-identical to the old wt path. ----
  {
    const int col0 = w * 64;
    float bi[4];
    #pragma unroll
    for (int nt = 0; nt < 4; ++nt) bi[nt] = out_bias[col0 + nt * 16 + li];

    f32x4 acc[4] = {{0.f,0.f,0.f,0.f},{0.f,0.f,0.f,0.f},{0.f,0.f,0.f,0.f},{0.f,0.f,0.f,0.f}};
    const unsigned short* arow = &s_resall[(li & 3) * 264 + g * 8];
    const float* wp = out_kernel + col0 + li;   // lane's base column

    #pragma unroll 2
    for (int ks = 0; ks < 8; ++ks) {
      s16x8 a = *(const s16x8*)(arow + ks * 32);
      const float* wk0 = wp + (ks * 32 + g * 8) * D;   // W[k0][c0]
      #pragma unroll
      for (int nt = 0; nt < 4; ++nt) {
        const float* wq = wk0 + nt * 16;
        union { s16x8 v; unsigned int u[4]; } ub;
        #pragma unroll
        for (int jj = 0; jj < 4; ++jj)
          ub.u[jj] = cvt_pk_bf16(wq[(2 * jj) * D], wq[(2 * jj + 1) * D]);
        acc[nt] = __builtin_amdgcn_mfma_f32_16x16x32_bf16(a, ub.v, acc[nt], 0, 0, 0);
      }
    }
    if (g == 0) {
      #pragma unroll
      for (int nt = 0; nt < 4; ++nt) {
        #pragma unroll
        for (int reg = 0; reg < 4; ++reg) {
          out[(be0 + reg) * D + col0 + nt * 16 + li] = silu(acc[nt][reg] + bi[nt]);
        }
      }
    }
  }
}

extern "C" void kernel_launch(void* const* d_in, const int* in_sizes, int n_in,
                              void* d_out, int out_size, void* d_ws, size_t ws_size,
                              hipStream_t stream) {
  const float* r            = (const float*)d_in[0];
  const float* r_nb         = (const float*)d_in[1];
  const float* ee_scales    = (const float*)d_in[2];
  const float* ee_kernel    = (const float*)d_in[3];
  const float* ee_bias      = (const float*)d_in[4];
  const float* beta_kernel  = (const float*)d_in[5];
  const float* beta_bias    = (const float*)d_in[6];
  const float* gamma_kernel = (const float*)d_in[7];
  const float* dense1_kernel= (const float*)d_in[8];
  const float* dense1_bias  = (const float*)d_in[9];
  const float* out_kernel   = (const float*)d_in[10];
  const float* out_bias     = (const float*)d_in[11];
  float* out = (float*)d_out;

  // single dispatch; d_ws unused
  hipLaunchKernelGGL(moon_fused, dim3(PAIRS / 4), dim3(256), 0, stream,
                     r, r_nb, ee_scales, ee_kernel, ee_bias,
                     beta_kernel, beta_bias, gamma_kernel,
                     dense1_kernel, dense1_bias, out_kernel, out_bias, out);
}

// Round 17
// 113.457 us; speedup vs baseline: 1.7205x; 1.0089x over previous
//
#include <hip/hip_runtime.h>
#include <hip/hip_bf16.h>

constexpr int NB   = 32;
constexpr int NENV = 8;
constexpr int F0   = 16;
constexpr int F1   = 32;
constexpr int D    = 256;
constexpr int PAIRS = 128 * 64;   // 8192
constexpr float CUT = 5.0f;

typedef float f32x4 __attribute__((ext_vector_type(4)));
typedef short s16x8 __attribute__((ext_vector_type(8)));

__device__ __forceinline__ float fast_rcp(float x) { return __builtin_amdgcn_rcpf(x); }
__device__ __forceinline__ float silu(float a) {
  return a * fast_rcp(1.0f + __expf(-a));
}
__device__ __forceinline__ float fast_tanh(float t) {
  return 1.0f - 2.0f * fast_rcp(__expf(2.0f * t) + 1.0f);
}
// gfx950 single-instruction packed fp32->bf16 (RNE)
__device__ __forceinline__ unsigned int cvt_pk_bf16(float a, float b) {
  unsigned int r;
  asm("v_cvt_pk_bf16_f32 %0, %1, %2" : "=v"(r) : "v"(a), "v"(b));
  return r;
}
__device__ __forceinline__ unsigned short f2bf(float f) {
  return (unsigned short)(cvt_pk_bf16(f, f) & 0xffffu);
}

// ---------------------------------------------------------------------------
// Single-dispatch fused kernel (r14, the session's validated best: 114.47 us,
// absmax 0.09375). One wave per (b,e) pair, 4 pairs/block, 2048 blocks.
//   phase 1: per-neighbor features; lane-halves split the k-range.
//   beta:    (hen @ beta_kernel + bias) * fcut via 4 MFMAs (bias at k=24).
//   phase 2: dual-MFMA (beta@G and inp@d1k replicated, x0.25 pre-scale).
//   tail:    out-GEMM; B-frags built directly from fp32 out_kernel via
//            cvt_pk_bf16 (bit-identical to a prep-kernel path, no ws).
// NOTE: r15/r16's 2-iteration loop variant of this exact body fails
// deterministically (absmax 9.09) for reasons not localizable at source
// level; do not re-apply that transformation without disasm diffing.
// ---------------------------------------------------------------------------
__global__ __launch_bounds__(256)
__attribute__((amdgpu_waves_per_eu(4, 4)))
void moon_fused(
    const float* __restrict__ r,            // [8192,3]
    const float* __restrict__ r_nb,         // [8192,32,3]
    const float* __restrict__ ee_scales,    // [8]
    const float* __restrict__ ee_kernel,    // [4,16]
    const float* __restrict__ ee_bias,      // [16]
    const float* __restrict__ beta_kernel,  // [24,32]
    const float* __restrict__ beta_bias,    // [32]
    const float* __restrict__ gamma_kernel, // [32,256]
    const float* __restrict__ dense1_kernel,// [4,256]
    const float* __restrict__ dense1_bias,  // [256]
    const float* __restrict__ out_kernel,   // [256,256] (W[k][c], read in tail)
    const float* __restrict__ out_bias,     // [256]
    float* __restrict__ out)                // [8192,256]
{
  __shared__ float s_eek[4 * F0];
  __shared__ float s_eeb[F0];
  __shared__ float s_is2[NENV];
  __shared__ unsigned short s_ghT[4][D * 8];        // [kslot g][d][8] bf16 (16 KB)
  __shared__ unsigned short s_d1kT[D * 8];          // [d][8] bf16 x0.25 (4 KB)
  __shared__ unsigned short s_bkh[4][F1 * 8];       // B-frags of beta_kernel+bias (2 KB)
  __shared__ unsigned short s_hb[4][4][NB * 8];     // [wave][g][row][8]: hen then betah (8 KB)
  __shared__ unsigned short s_inph[4][NB * 8];      // [wave][n][8] bf16 inp A-frag (2 KB)
  __shared__ float s_fcut[4][NB];                   // (0.5 KB)
  __shared__ unsigned short s_resall[4 * 264];      // [pair][264] bf16 res rows (2.1 KB)

  const int tid = threadIdx.x;
  const int w   = tid >> 6;
  const int l   = tid & 63;
  const int be  = blockIdx.x * 4 + w;
  const int be0 = blockIdx.x * 4;

  // ---- staging: small weights ----
  if (tid < 64)       s_eek[tid]      = ee_kernel[tid];
  else if (tid < 80)  s_eeb[tid - 64] = ee_bias[tid - 64];
  else if (tid < 88) { float s = ee_scales[tid - 80]; s_is2[tid - 80] = 1.0f / (s * s); }

  // ---- staging: beta_kernel -> B-frags (k-chunks; bias row at k=24) ----
  if (tid < 128) {
    const int c = tid & 31;
    const int g = tid >> 5;
    unsigned int q[4];
    if (g < 3) {
      float v[8];
      #pragma unroll
      for (int j = 0; j < 8; ++j) v[j] = beta_kernel[(g * 8 + j) * F1 + c];
      q[0] = cvt_pk_bf16(v[0], v[1]); q[1] = cvt_pk_bf16(v[2], v[3]);
      q[2] = cvt_pk_bf16(v[4], v[5]); q[3] = cvt_pk_bf16(v[6], v[7]);
    } else {
      q[0] = cvt_pk_bf16(beta_bias[c], 0.0f); q[1] = 0; q[2] = 0; q[3] = 0;
    }
    *(uint4*)&s_bkh[g][c * 8] = make_uint4(q[0], q[1], q[2], q[3]);
  }

  // ---- staging: gamma -> bf16 transposed, k-chunked (thread t owns row d=t) ----
  {
    const int d = tid;
    unsigned int pk[16];
    #pragma unroll
    for (int k2 = 0; k2 < 16; ++k2)
      pk[k2] = cvt_pk_bf16(gamma_kernel[(2 * k2 + 0) * D + d],
                           gamma_kernel[(2 * k2 + 1) * D + d]);
    #pragma unroll
    for (int g = 0; g < 4; ++g)
      *(uint4*)&s_ghT[g][d * 8] = make_uint4(pk[4*g], pk[4*g+1], pk[4*g+2], pk[4*g+3]);
  }
  // ---- staging: d1kT b-frag, PRE-SCALED by 0.25 (replication cancel; exact) ----
  {
    const int d = tid;
    unsigned int p0 = cvt_pk_bf16(0.25f * dense1_kernel[0 * D + d],
                                  0.25f * dense1_kernel[1 * D + d]);
    unsigned int p1 = cvt_pk_bf16(0.25f * dense1_kernel[2 * D + d],
                                  0.25f * dense1_kernel[3 * D + d]);
    unsigned int p2 = cvt_pk_bf16(0.25f * dense1_bias[d], 0.0f);  // k=4; k=5..7 zero
    *(uint4*)&s_d1kT[d * 8] = make_uint4(p0, p1, p2, 0u);
  }

  __syncthreads();

  const int li = l & 15;          // col-within-tile
  const int g  = l >> 4;          // k-chunk / C-row group

  // ---- phase 1: per-neighbor features -> s_hb (hen role), s_inph, s_fcut ----
  {
    const int n    = l & 31;
    const int half = l >> 5;     // k-range split
    float rx = r[be * 3 + 0];
    float ry = r[be * 3 + 1];
    float rz = r[be * 3 + 2];
    const float* rn = r_nb + (be * NB + n) * 3;
    float dx = rn[0] - rx;
    float dy = rn[1] - ry;
    float dz = rn[2] - rz;
    float d2 = dx * dx + dy * dy + dz * dz;
    float dist = sqrtf(d2);
    float feats[4] = {dist, dx, dy, dz};
    float h[8];
    #pragma unroll
    for (int j8 = 0; j8 < 8; ++j8) {
      int j = half * 8 + j8;
      float t = s_eeb[j];
      #pragma unroll
      for (int i = 0; i < 4; ++i) t += feats[i] * s_eek[i * F0 + j];
      h[j8] = fast_tanh(t);
    }
    unsigned int hp0 = cvt_pk_bf16(h[0], h[1]);
    unsigned int hp1 = cvt_pk_bf16(h[2], h[3]);
    unsigned int hp2 = cvt_pk_bf16(h[4], h[5]);
    unsigned int hp3 = cvt_pk_bf16(h[6], h[7]);
    if (half == 0) {
      *(uint4*)&s_hb[w][0][n * 8] = make_uint4(hp0, hp1, hp2, hp3);
      *(uint4*)&s_hb[w][3][n * 8] = make_uint4(0x3F80u, 0u, 0u, 0u);
      float lp  = log1pf(dist);
      float inv = lp / dist;
      unsigned int q0 = cvt_pk_bf16(lp, dx * inv);
      unsigned int q1 = cvt_pk_bf16(dy * inv, dz * inv);
      *(uint4*)&s_inph[w][n * 8] = make_uint4(q0, q1, 0x3F80u, 0u);
    } else {
      *(uint4*)&s_hb[w][1][n * 8] = make_uint4(hp0, hp1, hp2, hp3);
      float env[NENV];
      #pragma unroll
      for (int s = 0; s < NENV; ++s) env[s] = __expf(-d2 * s_is2[s]);
      unsigned int e0 = cvt_pk_bf16(env[0], env[1]);
      unsigned int e1 = cvt_pk_bf16(env[2], env[3]);
      unsigned int e2 = cvt_pk_bf16(env[4], env[5]);
      unsigned int e3 = cvt_pk_bf16(env[6], env[7]);
      *(uint4*)&s_hb[w][2][n * 8] = make_uint4(e0, e1, e2, e3);
      float xc = dist * (1.0f / CUT);
      s_fcut[w][n] = (xc < 1.0f)
                   ? 0.5f * (__cosf(3.14159265358979323846f * xc) + 1.0f)
                   : 0.0f;
    }
  }

  // ---- beta via MFMA: beta[n][c] = (hen @ bk + bias) * fcut[n] (wave-local) ----
  {
    s16x8 ah0 = *(const s16x8*)&s_hb[w][g][(0 * 16 + li) * 8];
    s16x8 ah1 = *(const s16x8*)&s_hb[w][g][(1 * 16 + li) * 8];
    s16x8 bb0 = *(const s16x8*)&s_bkh[g][(0 * 16 + li) * 8];
    s16x8 bb1 = *(const s16x8*)&s_bkh[g][(1 * 16 + li) * 8];
    f32x4 z = {0.f, 0.f, 0.f, 0.f};
    f32x4 c00 = __builtin_amdgcn_mfma_f32_16x16x32_bf16(ah0, bb0, z, 0, 0, 0);
    f32x4 c01 = __builtin_amdgcn_mfma_f32_16x16x32_bf16(ah0, bb1, z, 0, 0, 0);
    f32x4 c10 = __builtin_amdgcn_mfma_f32_16x16x32_bf16(ah1, bb0, z, 0, 0, 0);
    f32x4 c11 = __builtin_amdgcn_mfma_f32_16x16x32_bf16(ah1, bb1, z, 0, 0, 0);
    const int cl = li >> 3;
    const int sl = li & 7;
    #pragma unroll
    for (int reg = 0; reg < 4; ++reg) {
      int row0 = g * 4 + reg;
      int row1 = 16 + g * 4 + reg;
      float fc0 = s_fcut[w][row0];
      float fc1 = s_fcut[w][row1];
      s_hb[w][cl    ][row0 * 8 + sl] = f2bf(c00[reg] * fc0);
      s_hb[w][2 + cl][row0 * 8 + sl] = f2bf(c01[reg] * fc0);
      s_hb[w][cl    ][row1 * 8 + sl] = f2bf(c10[reg] * fc1);
      s_hb[w][2 + cl][row1 * 8 + sl] = f2bf(c11[reg] * fc1);
    }
  }

  // ---- phase 2: c = beta@G, f = inp@d1k+b (replicated x0.25); reduce ----
  {
    s16x8 a0 = *(const s16x8*)&s_hb[w][g][(0 * 16 + li) * 8];
    s16x8 a1 = *(const s16x8*)&s_hb[w][g][(1 * 16 + li) * 8];
    s16x8 ai0 = *(const s16x8*)&s_inph[w][(0 * 16 + li) * 8];
    s16x8 ai1 = *(const s16x8*)&s_inph[w][(1 * 16 + li) * 8];

    #pragma unroll 4
    for (int nt = 0; nt < 16; ++nt) {
      const int d = nt * 16 + li;
      s16x8 b  = *(const s16x8*)&s_ghT[g][d * 8];
      s16x8 bd = *(const s16x8*)&s_d1kT[d * 8];
      f32x4 z = {0.f, 0.f, 0.f, 0.f};
      f32x4 c0 = __builtin_amdgcn_mfma_f32_16x16x32_bf16(a0, b, z, 0, 0, 0);
      f32x4 c1 = __builtin_amdgcn_mfma_f32_16x16x32_bf16(a1, b, z, 0, 0, 0);
      f32x4 f0 = __builtin_amdgcn_mfma_f32_16x16x32_bf16(ai0, bd, z, 0, 0, 0);
      f32x4 f1 = __builtin_amdgcn_mfma_f32_16x16x32_bf16(ai1, bd, z, 0, 0, 0);
      float pv = 0.f;
      #pragma unroll
      for (int reg = 0; reg < 4; ++reg) {
        pv += silu(f0[reg]) * c0[reg];
        pv += silu(f1[reg]) * c1[reg];
      }
      pv += __shfl_xor(pv, 16);
      pv += __shfl_xor(pv, 32);
      if (g == (nt & 3)) s_resall[w * 264 + nt * 16 + li] = f2bf(pv);
    }
  }
  __syncthreads();   // all 4 pairs' res rows needed by every wave in the tail

  // ---- tail: out[be0+0..3, :] = silu(res @ W + b). B-frags built directly
  //      from fp32 out_kernel: slot j of (ks,nt) = bf16(W[ks*32+g*8+j][c]),
  //      c = col0 + nt*16 + li. ----
  {
    const int col0 = w * 64;
    float bi[4];
    #pragma unroll
    for (int nt = 0; nt < 4; ++nt) bi[nt] = out_bias[col0 + nt * 16 + li];

    f32x4 acc[4] = {{0.f,0.f,0.f,0.f},{0.f,0.f,0.f,0.f},{0.f,0.f,0.f,0.f},{0.f,0.f,0.f,0.f}};
    const unsigned short* arow = &s_resall[(li & 3) * 264 + g * 8];
    const float* wp = out_kernel + col0 + li;   // lane's base column

    #pragma unroll 2
    for (int ks = 0; ks < 8; ++ks) {
      s16x8 a = *(const s16x8*)(arow + ks * 32);
      const float* wk0 = wp + (ks * 32 + g * 8) * D;   // W[k0][c0]
      #pragma unroll
      for (int nt = 0; nt < 4; ++nt) {
        const float* wq = wk0 + nt * 16;
        union { s16x8 v; unsigned int u[4]; } ub;
        #pragma unroll
        for (int jj = 0; jj < 4; ++jj)
          ub.u[jj] = cvt_pk_bf16(wq[(2 * jj) * D], wq[(2 * jj + 1) * D]);
        acc[nt] = __builtin_amdgcn_mfma_f32_16x16x32_bf16(a, ub.v, acc[nt], 0, 0, 0);
      }
    }
    if (g == 0) {
      #pragma unroll
      for (int nt = 0; nt < 4; ++nt) {
        #pragma unroll
        for (int reg = 0; reg < 4; ++reg) {
          out[(be0 + reg) * D + col0 + nt * 16 + li] = silu(acc[nt][reg] + bi[nt]);
        }
      }
    }
  }
}

extern "C" void kernel_launch(void* const* d_in, const int* in_sizes, int n_in,
                              void* d_out, int out_size, void* d_ws, size_t ws_size,
                              hipStream_t stream) {
  const float* r            = (const float*)d_in[0];
  const float* r_nb         = (const float*)d_in[1];
  const float* ee_scales    = (const float*)d_in[2];
  const float* ee_kernel    = (const float*)d_in[3];
  const float* ee_bias      = (const float*)d_in[4];
  const float* beta_kernel  = (const float*)d_in[5];
  const float* beta_bias    = (const float*)d_in[6];
  const float* gamma_kernel = (const float*)d_in[7];
  const float* dense1_kernel= (const float*)d_in[8];
  const float* dense1_bias  = (const float*)d_in[9];
  const float* out_kernel   = (const float*)d_in[10];
  const float* out_bias     = (const float*)d_in[11];
  float* out = (float*)d_out;

  // single dispatch; d_ws unused
  hipLaunchKernelGGL(moon_fused, dim3(PAIRS / 4), dim3(256), 0, stream,
                     r, r_nb, ee_scales, ee_kernel, ee_bias,
                     beta_kernel, beta_bias, gamma_kernel,
                     dense1_kernel, dense1_bias, out_kernel, out_bias, out);
}